// Round 2
// baseline (1404.810 us; speedup 1.0000x reference)
//
#include <hip/hip_runtime.h>

// Problem constants (match reference).
#define NCUST 100000
#define NMERCH 50000
#define NEDGE 1000000
#define NTOT (NCUST + NMERCH)   // merchants first, then customers
#define HID 128
#define INC 128
#define INM 64
#define OUTD 64

// ---------------------------------------------------------------------------
// CSR build: histogram -> scan -> fill (bump allocation).
// Joint scan over [merchant counts (NM) | customer counts (NC)]; cm edges are
// exactly NEDGE so customer rows start at offset NEDGE in the shared csr[2E].
// ---------------------------------------------------------------------------

__global__ __launch_bounds__(256) void hist_kernel(const int* __restrict__ cm_dst,
                                                   const int* __restrict__ mc_dst,
                                                   int* __restrict__ counts) {
    int idx = blockIdx.x * 256 + threadIdx.x;
    if (idx < NEDGE) {
        atomicAdd(&counts[cm_dst[idx]], 1);
    } else if (idx < 2 * NEDGE) {
        atomicAdd(&counts[NMERCH + mc_dst[idx - NEDGE]], 1);
    }
}

__global__ __launch_bounds__(256) void block_sums_kernel(const int* __restrict__ counts,
                                                         int* __restrict__ bsum) {
    int t = threadIdx.x;
    int idx = blockIdx.x * 1024 + t * 4;
    int4 v = make_int4(0, 0, 0, 0);
    if (idx + 3 < NTOT) {
        v = *(const int4*)(counts + idx);
    } else if (idx < NTOT) {
        v.x = counts[idx];
        if (idx + 1 < NTOT) v.y = counts[idx + 1];
        if (idx + 2 < NTOT) v.z = counts[idx + 2];
    }
    int s = v.x + v.y + v.z + v.w;
    __shared__ int sh[256];
    sh[t] = s;
    __syncthreads();
    for (int off = 128; off > 0; off >>= 1) {
        if (t < off) sh[t] += sh[t + off];
        __syncthreads();
    }
    if (t == 0) bsum[blockIdx.x] = sh[0];
}

__global__ __launch_bounds__(256) void scan_partials_kernel(const int* __restrict__ bsum,
                                                            int* __restrict__ bpre, int n) {
    int t = threadIdx.x;
    __shared__ int sh[256];
    int v = (t < n) ? bsum[t] : 0;
    sh[t] = v;
    __syncthreads();
    for (int off = 1; off < 256; off <<= 1) {
        int val = (t >= off) ? sh[t - off] : 0;
        __syncthreads();
        sh[t] += val;
        __syncthreads();
    }
    if (t < n) bpre[t] = sh[t] - v;  // exclusive prefix
}

__global__ __launch_bounds__(256) void scan_chunks_kernel(const int* __restrict__ counts,
                                                          const int* __restrict__ bpre,
                                                          int* __restrict__ ro,
                                                          int* __restrict__ cursor) {
    int t = threadIdx.x;
    int idx = blockIdx.x * 1024 + t * 4;
    int4 v = make_int4(0, 0, 0, 0);
    if (idx + 3 < NTOT) {
        v = *(const int4*)(counts + idx);
    } else if (idx < NTOT) {
        v.x = counts[idx];
        if (idx + 1 < NTOT) v.y = counts[idx + 1];
        if (idx + 2 < NTOT) v.z = counts[idx + 2];
    }
    int mysum = v.x + v.y + v.z + v.w;
    __shared__ int sh[256];
    sh[t] = mysum;
    __syncthreads();
    for (int off = 1; off < 256; off <<= 1) {
        int val = (t >= off) ? sh[t - off] : 0;
        __syncthreads();
        sh[t] += val;
        __syncthreads();
    }
    int base = bpre[blockIdx.x] + (sh[t] - mysum);
    int p0 = base;
    int p1 = p0 + v.x;
    int p2 = p1 + v.y;
    int p3 = p2 + v.z;
    if (idx < NTOT)     { ro[idx]     = p0; cursor[idx]     = p0; }
    if (idx + 1 < NTOT) { ro[idx + 1] = p1; cursor[idx + 1] = p1; }
    if (idx + 2 < NTOT) { ro[idx + 2] = p2; cursor[idx + 2] = p2; }
    if (idx + 3 < NTOT) { ro[idx + 3] = p3; cursor[idx + 3] = p3; }
    if (blockIdx.x == 0 && t == 0) ro[NTOT] = 2 * NEDGE;
}

__global__ __launch_bounds__(256) void fill_kernel(const int* __restrict__ cm_src,
                                                   const int* __restrict__ cm_dst,
                                                   const int* __restrict__ mc_src,
                                                   const int* __restrict__ mc_dst,
                                                   int* __restrict__ cursor,
                                                   int* __restrict__ csr) {
    int idx = blockIdx.x * 256 + threadIdx.x;
    if (idx < NEDGE) {
        int d = cm_dst[idx];
        int p = atomicAdd(&cursor[d], 1);
        csr[p] = cm_src[idx];
    } else if (idx < 2 * NEDGE) {
        int e = idx - NEDGE;
        int d = mc_dst[e];
        int p = atomicAdd(&cursor[NMERCH + d], 1);
        csr[p] = mc_src[e];
    }
}

// ---------------------------------------------------------------------------
// Aggregations: one wave per destination node, register accumulate, unroll 4.
// ---------------------------------------------------------------------------

// mean over cm edges of x_customer rows (128 f32) -> t_agg_m [NM,128]
__global__ __launch_bounds__(256) void agg_cm_kernel(const float* __restrict__ xc,
                                                     const int* __restrict__ csr,
                                                     const int* __restrict__ ro,
                                                     float* __restrict__ aggm) {
    int node = blockIdx.x * 4 + (threadIdx.x >> 6);
    int lane = threadIdx.x & 63;
    if (node >= NMERCH) return;
    int start = ro[node], end = ro[node + 1];
    float2 a0 = {0.f, 0.f}, a1 = {0.f, 0.f}, a2 = {0.f, 0.f}, a3 = {0.f, 0.f};
    int e = start;
    for (; e + 4 <= end; e += 4) {
        int s0 = csr[e], s1 = csr[e + 1], s2 = csr[e + 2], s3 = csr[e + 3];
        float2 v0 = *(const float2*)(xc + (size_t)s0 * INC + lane * 2);
        float2 v1 = *(const float2*)(xc + (size_t)s1 * INC + lane * 2);
        float2 v2 = *(const float2*)(xc + (size_t)s2 * INC + lane * 2);
        float2 v3 = *(const float2*)(xc + (size_t)s3 * INC + lane * 2);
        a0.x += v0.x; a0.y += v0.y;
        a1.x += v1.x; a1.y += v1.y;
        a2.x += v2.x; a2.y += v2.y;
        a3.x += v3.x; a3.y += v3.y;
    }
    for (; e < end; ++e) {
        int s0 = csr[e];
        float2 v0 = *(const float2*)(xc + (size_t)s0 * INC + lane * 2);
        a0.x += v0.x; a0.y += v0.y;
    }
    int deg = end - start;
    float cnt = (float)(deg > 0 ? deg : 1);
    float2 o;
    o.x = (a0.x + a1.x + a2.x + a3.x) / cnt;
    o.y = (a0.y + a1.y + a2.y + a3.y) / cnt;
    *(float2*)(aggm + (size_t)node * HID + lane * 2) = o;
}

// Fused mc-direction gather: mean of x_merchant rows (64 f32) -> agg_c [NC,64]
// and of t2 = h_m @ W2mc_l rows (128 f32) -> aggT2 [NC,128]  (transform-first).
__global__ __launch_bounds__(256) void agg_mc_kernel(const float* __restrict__ xm,
                                                     const float* __restrict__ t2,
                                                     const int* __restrict__ csr,
                                                     const int* __restrict__ ro,
                                                     float* __restrict__ agg_c,
                                                     float* __restrict__ aggT2) {
    int node = blockIdx.x * 4 + (threadIdx.x >> 6);
    int lane = threadIdx.x & 63;
    if (node >= NCUST) return;
    int start = ro[NMERCH + node], end = ro[NMERCH + node + 1];
    float a0 = 0.f, a1 = 0.f, a2 = 0.f, a3 = 0.f;
    float2 h0 = {0.f, 0.f}, h1 = {0.f, 0.f}, h2 = {0.f, 0.f}, h3 = {0.f, 0.f};
    int e = start;
    for (; e + 4 <= end; e += 4) {
        int s0 = csr[e], s1 = csr[e + 1], s2 = csr[e + 2], s3 = csr[e + 3];
        a0 += xm[(size_t)s0 * INM + lane];
        a1 += xm[(size_t)s1 * INM + lane];
        a2 += xm[(size_t)s2 * INM + lane];
        a3 += xm[(size_t)s3 * INM + lane];
        float2 v0 = *(const float2*)(t2 + (size_t)s0 * HID + lane * 2);
        float2 v1 = *(const float2*)(t2 + (size_t)s1 * HID + lane * 2);
        float2 v2 = *(const float2*)(t2 + (size_t)s2 * HID + lane * 2);
        float2 v3 = *(const float2*)(t2 + (size_t)s3 * HID + lane * 2);
        h0.x += v0.x; h0.y += v0.y;
        h1.x += v1.x; h1.y += v1.y;
        h2.x += v2.x; h2.y += v2.y;
        h3.x += v3.x; h3.y += v3.y;
    }
    for (; e < end; ++e) {
        int s0 = csr[e];
        a0 += xm[(size_t)s0 * INM + lane];
        float2 v0 = *(const float2*)(t2 + (size_t)s0 * HID + lane * 2);
        h0.x += v0.x; h0.y += v0.y;
    }
    int deg = end - start;
    float cnt = (float)(deg > 0 ? deg : 1);
    agg_c[(size_t)node * INM + lane] = (a0 + a1 + a2 + a3) / cnt;
    float2 o;
    o.x = (h0.x + h1.x + h2.x + h3.x) / cnt;
    o.y = (h0.y + h1.y + h2.y + h3.y) / cnt;
    *(float2*)(aggT2 + (size_t)node * HID + lane * 2) = o;
}

// ---------------------------------------------------------------------------
// GEMMs. Thread owns one output column for R=8 rows; block grid-strides over
// row tiles so weights are staged in LDS ONCE per block (not per tile).
// All row counts divide the tile size exactly -> no bounds checks.
// ---------------------------------------------------------------------------

__device__ __forceinline__ void stage_w(const float* __restrict__ W, float* sW, int nflt) {
    for (int i = threadIdx.x * 4; i < nflt; i += 1024)
        *(float4*)&sW[i] = *(const float4*)&W[i];
}

// out[row,j] = [relu]( A[row,:] @ W + bias[j] + add[row*add_ld + j] )
template <int K, int NOUT, bool RELU, bool HASBIAS, bool HASADD>
__global__ __launch_bounds__(256) void mm_kernel(const float* __restrict__ A,
                                                 const float* __restrict__ W,
                                                 const float* __restrict__ bias,
                                                 const float* __restrict__ add, int add_ld,
                                                 float* __restrict__ out, int ntiles) {
    __shared__ float sW[K * NOUT];
    stage_w(W, sW, K * NOUT);
    __syncthreads();

    constexpr int G = 256 / NOUT;
    constexpr int R = 8;
    constexpr int TR = G * R;
    const int j = threadIdx.x % NOUT;
    const int rg = threadIdx.x / NOUT;
    const float b = HASBIAS ? bias[j] : 0.f;

    for (int tile = blockIdx.x; tile < ntiles; tile += gridDim.x) {
        const int base = tile * TR + rg * R;
        float acc[R];
#pragma unroll
        for (int r = 0; r < R; ++r) acc[r] = 0.f;

        for (int kq = 0; kq < K / 4; ++kq) {
            float4 iv[R];
#pragma unroll
            for (int r = 0; r < R; ++r)
                iv[r] = ((const float4*)A)[(size_t)(base + r) * (K / 4) + kq];
#pragma unroll
            for (int m = 0; m < 4; ++m) {
                float w = sW[(kq * 4 + m) * NOUT + j];
#pragma unroll
                for (int r = 0; r < R; ++r) acc[r] = fmaf((&iv[r].x)[m], w, acc[r]);
            }
        }
#pragma unroll
        for (int r = 0; r < R; ++r) {
            float v = acc[r] + b;
            if (HASADD) v += add[(size_t)(base + r) * add_ld + j];
            if (RELU) v = fmaxf(v, 0.f);
            out[(size_t)(base + r) * NOUT + j] = v;
        }
    }
}

// Fused SAGE linear: out = relu( A @ Wa + bias + B @ Wb ), two LDS phases.
// Phase 1 stores partial (A@Wa + bias) to out; phase 2 restages LDS with Wb,
// re-reads only this thread's own rows (self-RMW, race-free), adds B@Wb, relu.
template <int KA, int KB, int NOUT, bool RELU>
__global__ __launch_bounds__(256) void sage_mm_kernel(const float* __restrict__ A,
                                                      const float* __restrict__ Wa,
                                                      const float* __restrict__ bias,
                                                      const float* __restrict__ B,
                                                      const float* __restrict__ Wb,
                                                      float* __restrict__ out, int ntiles) {
    constexpr int KMAX = (KA > KB) ? KA : KB;
    __shared__ float sW[KMAX * NOUT];

    constexpr int G = 256 / NOUT;
    constexpr int R = 8;
    constexpr int TR = G * R;
    const int j = threadIdx.x % NOUT;
    const int rg = threadIdx.x / NOUT;
    const float b = bias[j];

    // ---- phase 1: out = A @ Wa + bias ----
    stage_w(Wa, sW, KA * NOUT);
    __syncthreads();
    for (int tile = blockIdx.x; tile < ntiles; tile += gridDim.x) {
        const int base = tile * TR + rg * R;
        float acc[R];
#pragma unroll
        for (int r = 0; r < R; ++r) acc[r] = b;
        for (int kq = 0; kq < KA / 4; ++kq) {
            float4 iv[R];
#pragma unroll
            for (int r = 0; r < R; ++r)
                iv[r] = ((const float4*)A)[(size_t)(base + r) * (KA / 4) + kq];
#pragma unroll
            for (int m = 0; m < 4; ++m) {
                float w = sW[(kq * 4 + m) * NOUT + j];
#pragma unroll
                for (int r = 0; r < R; ++r) acc[r] = fmaf((&iv[r].x)[m], w, acc[r]);
            }
        }
#pragma unroll
        for (int r = 0; r < R; ++r) out[(size_t)(base + r) * NOUT + j] = acc[r];
    }

    // ---- phase 2: out = [relu](out + B @ Wb) ----
    __syncthreads();
    stage_w(Wb, sW, KB * NOUT);
    __syncthreads();
    for (int tile = blockIdx.x; tile < ntiles; tile += gridDim.x) {
        const int base = tile * TR + rg * R;
        float acc[R];
#pragma unroll
        for (int r = 0; r < R; ++r) acc[r] = 0.f;
        for (int kq = 0; kq < KB / 4; ++kq) {
            float4 iv[R];
#pragma unroll
            for (int r = 0; r < R; ++r)
                iv[r] = ((const float4*)B)[(size_t)(base + r) * (KB / 4) + kq];
#pragma unroll
            for (int m = 0; m < 4; ++m) {
                float w = sW[(kq * 4 + m) * NOUT + j];
#pragma unroll
                for (int r = 0; r < R; ++r) acc[r] = fmaf((&iv[r].x)[m], w, acc[r]);
            }
        }
#pragma unroll
        for (int r = 0; r < R; ++r) {
            float v = out[(size_t)(base + r) * NOUT + j] + acc[r];
            if (RELU) v = fmaxf(v, 0.f);
            out[(size_t)(base + r) * NOUT + j] = v;
        }
    }
}

// ---------------------------------------------------------------------------
// Launch
// ---------------------------------------------------------------------------

extern "C" void kernel_launch(void* const* d_in, const int* in_sizes, int n_in,
                              void* d_out, int out_size, void* d_ws, size_t ws_size,
                              hipStream_t stream) {
    const float* x_c    = (const float*)d_in[0];
    const float* x_m    = (const float*)d_in[1];
    const float* W1cm_l = (const float*)d_in[2];
    const float* W1cm_r = (const float*)d_in[3];
    const float* b1_cm  = (const float*)d_in[4];
    const float* W1mc_l = (const float*)d_in[5];
    const float* W1mc_r = (const float*)d_in[6];
    const float* b1_mc  = (const float*)d_in[7];
    // d_in[8..10] = W2cm_l, W2cm_r, b2_cm : dead inputs (never reach the output)
    const float* W2mc_l = (const float*)d_in[11];
    const float* W2mc_r = (const float*)d_in[12];
    const float* b2_mc  = (const float*)d_in[13];
    const float* Wout   = (const float*)d_in[14];
    const float* bout   = (const float*)d_in[15];
    const int* cm_src   = (const int*)d_in[16];
    const int* cm_dst   = (const int*)d_in[17];
    const int* mc_src   = (const int*)d_in[18];
    const int* mc_dst   = (const int*)d_in[19];
    float* out = (float*)d_out;

    // Workspace carve-up (~215 MB peak, with overlays).
    char* ws = (char*)d_ws;
    size_t off = 0;
    auto bump = [&](size_t bytes) -> char* {
        off = (off + 255) & ~(size_t)255;
        char* p = ws + off;
        off += bytes;
        return p;
    };
    int* counts = (int*)bump((size_t)NTOT * 4);
    int* ro     = (int*)bump((size_t)(NTOT + 1) * 4);
    int* cursor = (int*)bump((size_t)NTOT * 4);
    int* bsum   = (int*)bump(256 * 4);
    int* bpre   = (int*)bump(256 * 4);
    int* csr    = (int*)bump((size_t)2 * NEDGE * 4);
    float* bufA  = (float*)bump((size_t)NCUST * HID * 4);  // t_agg_m | h_m ; later h_c2
    float* t2    = (float*)bump((size_t)NMERCH * HID * 4);
    float* agg_c = (float*)bump((size_t)NCUST * INM * 4);
    float* aggT2 = (float*)bump((size_t)NCUST * HID * 4);
    float* h_c   = (float*)bump((size_t)NCUST * HID * 4);

    float* t_agg_m = bufA;                          // [NM,128], dead after sage_mm #1
    float* h_m     = bufA + (size_t)NMERCH * HID;   // [NM,128], dead after t2 GEMM
    float* h_c2    = bufA;                          // [NC,128], overlays both

    const int NBLK = (NTOT + 1023) / 1024;  // 147

    // --- CSR build ---
    hipMemsetAsync(counts, 0, (size_t)NTOT * 4, stream);
    hist_kernel<<<(2 * NEDGE + 255) / 256, 256, 0, stream>>>(cm_dst, mc_dst, counts);
    block_sums_kernel<<<NBLK, 256, 0, stream>>>(counts, bsum);
    scan_partials_kernel<<<1, 256, 0, stream>>>(bsum, bpre, NBLK);
    scan_chunks_kernel<<<NBLK, 256, 0, stream>>>(counts, bpre, ro, cursor);
    fill_kernel<<<(2 * NEDGE + 255) / 256, 256, 0, stream>>>(cm_src, cm_dst, mc_src, mc_dst,
                                                             cursor, csr);

    // --- layer 1, cm: h_m = relu(mean_cm(x_c) @ W1cm_l + b1_cm + x_m @ W1cm_r) ---
    agg_cm_kernel<<<NMERCH / 4, 256, 0, stream>>>(x_c, csr, ro, t_agg_m);
    sage_mm_kernel<128, 64, 128, true><<<512, 256, 0, stream>>>(
        t_agg_m, W1cm_l, b1_cm, x_m, W1cm_r, h_m, NMERCH / 16);

    // --- layer 2 transform-first: t2 = h_m @ W2mc_l (mean is linear) ---
    mm_kernel<128, 128, false, false, false><<<512, 256, 0, stream>>>(
        h_m, W2mc_l, nullptr, nullptr, 0, t2, NMERCH / 16);

    // --- fused mc gathers: agg_c = mean_mc(x_m), aggT2 = mean_mc(t2) ---
    agg_mc_kernel<<<NCUST / 4, 256, 0, stream>>>(x_m, t2, csr, ro, agg_c, aggT2);

    // --- layer 1, mc: h_c = relu(agg_c @ W1mc_l + b1_mc + x_c @ W1mc_r) ---
    sage_mm_kernel<64, 128, 128, true><<<512, 256, 0, stream>>>(
        agg_c, W1mc_l, b1_mc, x_c, W1mc_r, h_c, NCUST / 16);

    // --- layer 2: h_c2 = aggT2 + b2_mc + h_c @ W2mc_r ---
    mm_kernel<128, 128, false, true, true><<<512, 256, 0, stream>>>(
        h_c, W2mc_r, b2_mc, aggT2, HID, h_c2, NCUST / 16);

    // --- output: out = h_c2 @ Wout + bout ---
    mm_kernel<128, 64, false, true, false><<<1024, 256, 0, stream>>>(
        h_c2, Wout, bout, nullptr, 0, out, NCUST / 32);
}

// Round 3
// 831.242 us; speedup vs baseline: 1.6900x; 1.6900x over previous
//
#include <hip/hip_runtime.h>

// Problem constants (match reference).
#define NCUST 100000
#define NMERCH 50000
#define NEDGE 1000000
#define NTOT (NCUST + NMERCH)   // merchants first, then customers
#define HID 128
#define INC 128
#define INM 64
#define OUTD 64

// ---------------------------------------------------------------------------
// CSR build: histogram -> scan -> fill (bump allocation).
// ---------------------------------------------------------------------------

__global__ __launch_bounds__(256) void hist_kernel(const int* __restrict__ cm_dst,
                                                   const int* __restrict__ mc_dst,
                                                   int* __restrict__ counts) {
    int idx = blockIdx.x * 256 + threadIdx.x;
    if (idx < NEDGE) {
        atomicAdd(&counts[cm_dst[idx]], 1);
    } else if (idx < 2 * NEDGE) {
        atomicAdd(&counts[NMERCH + mc_dst[idx - NEDGE]], 1);
    }
}

__global__ __launch_bounds__(256) void block_sums_kernel(const int* __restrict__ counts,
                                                         int* __restrict__ bsum) {
    int t = threadIdx.x;
    int idx = blockIdx.x * 1024 + t * 4;
    int4 v = make_int4(0, 0, 0, 0);
    if (idx + 3 < NTOT) {
        v = *(const int4*)(counts + idx);
    } else if (idx < NTOT) {
        v.x = counts[idx];
        if (idx + 1 < NTOT) v.y = counts[idx + 1];
        if (idx + 2 < NTOT) v.z = counts[idx + 2];
    }
    int s = v.x + v.y + v.z + v.w;
    __shared__ int sh[256];
    sh[t] = s;
    __syncthreads();
    for (int off = 128; off > 0; off >>= 1) {
        if (t < off) sh[t] += sh[t + off];
        __syncthreads();
    }
    if (t == 0) bsum[blockIdx.x] = sh[0];
}

__global__ __launch_bounds__(256) void scan_partials_kernel(const int* __restrict__ bsum,
                                                            int* __restrict__ bpre, int n) {
    int t = threadIdx.x;
    __shared__ int sh[256];
    int v = (t < n) ? bsum[t] : 0;
    sh[t] = v;
    __syncthreads();
    for (int off = 1; off < 256; off <<= 1) {
        int val = (t >= off) ? sh[t - off] : 0;
        __syncthreads();
        sh[t] += val;
        __syncthreads();
    }
    if (t < n) bpre[t] = sh[t] - v;  // exclusive prefix
}

__global__ __launch_bounds__(256) void scan_chunks_kernel(const int* __restrict__ counts,
                                                          const int* __restrict__ bpre,
                                                          int* __restrict__ ro,
                                                          int* __restrict__ cursor) {
    int t = threadIdx.x;
    int idx = blockIdx.x * 1024 + t * 4;
    int4 v = make_int4(0, 0, 0, 0);
    if (idx + 3 < NTOT) {
        v = *(const int4*)(counts + idx);
    } else if (idx < NTOT) {
        v.x = counts[idx];
        if (idx + 1 < NTOT) v.y = counts[idx + 1];
        if (idx + 2 < NTOT) v.z = counts[idx + 2];
    }
    int mysum = v.x + v.y + v.z + v.w;
    __shared__ int sh[256];
    sh[t] = mysum;
    __syncthreads();
    for (int off = 1; off < 256; off <<= 1) {
        int val = (t >= off) ? sh[t - off] : 0;
        __syncthreads();
        sh[t] += val;
        __syncthreads();
    }
    int base = bpre[blockIdx.x] + (sh[t] - mysum);
    int p0 = base;
    int p1 = p0 + v.x;
    int p2 = p1 + v.y;
    int p3 = p2 + v.z;
    if (idx < NTOT)     { ro[idx]     = p0; cursor[idx]     = p0; }
    if (idx + 1 < NTOT) { ro[idx + 1] = p1; cursor[idx + 1] = p1; }
    if (idx + 2 < NTOT) { ro[idx + 2] = p2; cursor[idx + 2] = p2; }
    if (idx + 3 < NTOT) { ro[idx + 3] = p3; cursor[idx + 3] = p3; }
    if (blockIdx.x == 0 && t == 0) ro[NTOT] = 2 * NEDGE;
}

__global__ __launch_bounds__(256) void fill_kernel(const int* __restrict__ cm_src,
                                                   const int* __restrict__ cm_dst,
                                                   const int* __restrict__ mc_src,
                                                   const int* __restrict__ mc_dst,
                                                   int* __restrict__ cursor,
                                                   int* __restrict__ csr) {
    int idx = blockIdx.x * 256 + threadIdx.x;
    if (idx < NEDGE) {
        int d = cm_dst[idx];
        int p = atomicAdd(&cursor[d], 1);
        csr[p] = cm_src[idx];
    } else if (idx < 2 * NEDGE) {
        int e = idx - NEDGE;
        int d = mc_dst[e];
        int p = atomicAdd(&cursor[NMERCH + d], 1);
        csr[p] = mc_src[e];
    }
}

// ---------------------------------------------------------------------------
// Aggregations: one wave per destination node, register accumulate, unroll 4.
// ---------------------------------------------------------------------------

__global__ __launch_bounds__(256) void agg_cm_kernel(const float* __restrict__ xc,
                                                     const int* __restrict__ csr,
                                                     const int* __restrict__ ro,
                                                     float* __restrict__ aggm) {
    int node = blockIdx.x * 4 + (threadIdx.x >> 6);
    int lane = threadIdx.x & 63;
    if (node >= NMERCH) return;
    int start = ro[node], end = ro[node + 1];
    float2 a0 = {0.f, 0.f}, a1 = {0.f, 0.f}, a2 = {0.f, 0.f}, a3 = {0.f, 0.f};
    int e = start;
    for (; e + 4 <= end; e += 4) {
        int s0 = csr[e], s1 = csr[e + 1], s2 = csr[e + 2], s3 = csr[e + 3];
        float2 v0 = *(const float2*)(xc + (size_t)s0 * INC + lane * 2);
        float2 v1 = *(const float2*)(xc + (size_t)s1 * INC + lane * 2);
        float2 v2 = *(const float2*)(xc + (size_t)s2 * INC + lane * 2);
        float2 v3 = *(const float2*)(xc + (size_t)s3 * INC + lane * 2);
        a0.x += v0.x; a0.y += v0.y;
        a1.x += v1.x; a1.y += v1.y;
        a2.x += v2.x; a2.y += v2.y;
        a3.x += v3.x; a3.y += v3.y;
    }
    for (; e < end; ++e) {
        int s0 = csr[e];
        float2 v0 = *(const float2*)(xc + (size_t)s0 * INC + lane * 2);
        a0.x += v0.x; a0.y += v0.y;
    }
    int deg = end - start;
    float cnt = (float)(deg > 0 ? deg : 1);
    float2 o;
    o.x = (a0.x + a1.x + a2.x + a3.x) / cnt;
    o.y = (a0.y + a1.y + a2.y + a3.y) / cnt;
    *(float2*)(aggm + (size_t)node * HID + lane * 2) = o;
}

__global__ __launch_bounds__(256) void agg_mc_kernel(const float* __restrict__ xm,
                                                     const float* __restrict__ t2,
                                                     const int* __restrict__ csr,
                                                     const int* __restrict__ ro,
                                                     float* __restrict__ agg_c,
                                                     float* __restrict__ aggT2) {
    int node = blockIdx.x * 4 + (threadIdx.x >> 6);
    int lane = threadIdx.x & 63;
    if (node >= NCUST) return;
    int start = ro[NMERCH + node], end = ro[NMERCH + node + 1];
    float a0 = 0.f, a1 = 0.f, a2 = 0.f, a3 = 0.f;
    float2 h0 = {0.f, 0.f}, h1 = {0.f, 0.f}, h2 = {0.f, 0.f}, h3 = {0.f, 0.f};
    int e = start;
    for (; e + 4 <= end; e += 4) {
        int s0 = csr[e], s1 = csr[e + 1], s2 = csr[e + 2], s3 = csr[e + 3];
        a0 += xm[(size_t)s0 * INM + lane];
        a1 += xm[(size_t)s1 * INM + lane];
        a2 += xm[(size_t)s2 * INM + lane];
        a3 += xm[(size_t)s3 * INM + lane];
        float2 v0 = *(const float2*)(t2 + (size_t)s0 * HID + lane * 2);
        float2 v1 = *(const float2*)(t2 + (size_t)s1 * HID + lane * 2);
        float2 v2 = *(const float2*)(t2 + (size_t)s2 * HID + lane * 2);
        float2 v3 = *(const float2*)(t2 + (size_t)s3 * HID + lane * 2);
        h0.x += v0.x; h0.y += v0.y;
        h1.x += v1.x; h1.y += v1.y;
        h2.x += v2.x; h2.y += v2.y;
        h3.x += v3.x; h3.y += v3.y;
    }
    for (; e < end; ++e) {
        int s0 = csr[e];
        a0 += xm[(size_t)s0 * INM + lane];
        float2 v0 = *(const float2*)(t2 + (size_t)s0 * HID + lane * 2);
        h0.x += v0.x; h0.y += v0.y;
    }
    int deg = end - start;
    float cnt = (float)(deg > 0 ? deg : 1);
    agg_c[(size_t)node * INM + lane] = (a0 + a1 + a2 + a3) / cnt;
    float2 o;
    o.x = (h0.x + h1.x + h2.x + h3.x) / cnt;
    o.y = (h0.y + h1.y + h2.y + h3.y) / cnt;
    *(float2*)(aggT2 + (size_t)node * HID + lane * 2) = o;
}

// ---------------------------------------------------------------------------
// Register-tiled fp32 GEMM with fused concat-K (two A operands, two weights):
//   out[M,NOUT] = [relu]( A[M,KA]@WA + B[M,KB]@WB (+bias) (+add) )
// Block: 256 threads -> tile TROWS x NOUT; thread: 8 rows x 8 cols (split into
// two col-quads NOUT/2 apart to keep LDS W-reads 2-way conflict-free).
// A staged transposed in LDS (pad +4: conflict-free reads, 2-way writes);
// W staged per 16-k step (tiny, L2-hot). Next step's global loads issue
// before the compute phase (latency hidden under 16x(4 ds_read + 64 fma)).
// ---------------------------------------------------------------------------

template <int KA, int KB, int NOUT, bool RELU, bool HASBIAS, bool HASADD>
__global__ __launch_bounds__(256) void gemm_kernel(const float* __restrict__ A,
                                                   const float* __restrict__ B,
                                                   const float* __restrict__ WA,
                                                   const float* __restrict__ WB,
                                                   const float* __restrict__ bias,
                                                   const float* __restrict__ add,
                                                   float* __restrict__ out, int M) {
    constexpr int CG = NOUT / 8;    // col-groups
    constexpr int RG = 256 / CG;    // row-groups
    constexpr int TROWS = RG * 8;   // tile rows (128 for NOUT=128, 256 for NOUT=64)
    constexpr int NFA = TROWS / 64; // A float4 per thread per k-step
    constexpr int NFW = NOUT / 64;  // W float4 per thread per k-step
    constexpr int AST = TROWS + 4;  // padded LDS stride (keeps 16B alignment)
    constexpr int NSA = KA / 16, NSB = KB / 16, NS = NSA + NSB;

    __shared__ float At[16 * AST];
    __shared__ float Wt[16 * NOUT];

    const int t = threadIdx.x;
    const int tc = t % CG;
    const int tr = t / CG;
    const int rowbase = blockIdx.x * TROWS;

    float4 pa[NFA];
    float4 pw[NFW];

    auto gload = [&](int s) {
        const float* asrc;
        const float* wsrc;
        int lda, ks;
        if (s < NSA) { asrc = A; wsrc = WA; lda = KA; ks = s * 16; }
        else         { asrc = B; wsrc = WB; lda = KB; ks = (s - NSA) * 16; }
#pragma unroll
        for (int f = 0; f < NFA; ++f) {
            int idx = t + 256 * f;
            int ar = idx >> 2, akq = idx & 3;
            int grow = rowbase + ar;
            if (grow < M) {
                pa[f] = *(const float4*)&asrc[(size_t)grow * lda + ks + akq * 4];
            } else {
                pa[f] = make_float4(0.f, 0.f, 0.f, 0.f);
            }
        }
#pragma unroll
        for (int f = 0; f < NFW; ++f) {
            int idx = t + 256 * f;
            int wk = idx / (NOUT / 4), wcq = idx % (NOUT / 4);
            pw[f] = *(const float4*)&wsrc[(size_t)(ks + wk) * NOUT + wcq * 4];
        }
    };

    float4 acc[8][2];
#pragma unroll
    for (int r = 0; r < 8; ++r) {
        acc[r][0] = make_float4(0.f, 0.f, 0.f, 0.f);
        acc[r][1] = make_float4(0.f, 0.f, 0.f, 0.f);
    }

    gload(0);
    for (int s = 0; s < NS; ++s) {
        __syncthreads();
#pragma unroll
        for (int f = 0; f < NFA; ++f) {
            int idx = t + 256 * f;
            int ar = idx >> 2, akq = idx & 3;
            At[(akq * 4 + 0) * AST + ar] = pa[f].x;
            At[(akq * 4 + 1) * AST + ar] = pa[f].y;
            At[(akq * 4 + 2) * AST + ar] = pa[f].z;
            At[(akq * 4 + 3) * AST + ar] = pa[f].w;
        }
#pragma unroll
        for (int f = 0; f < NFW; ++f) {
            int idx = t + 256 * f;
            int wk = idx / (NOUT / 4), wcq = idx % (NOUT / 4);
            *(float4*)&Wt[wk * NOUT + wcq * 4] = pw[f];
        }
        if (s + 1 < NS) gload(s + 1);
        __syncthreads();
#pragma unroll
        for (int k = 0; k < 16; ++k) {
            float4 av0 = *(const float4*)&At[k * AST + tr * 8];
            float4 av1 = *(const float4*)&At[k * AST + tr * 8 + 4];
            float4 w0 = *(const float4*)&Wt[k * NOUT + tc * 4];
            float4 w1 = *(const float4*)&Wt[k * NOUT + NOUT / 2 + tc * 4];
            const float ar8[8] = {av0.x, av0.y, av0.z, av0.w, av1.x, av1.y, av1.z, av1.w};
#pragma unroll
            for (int r = 0; r < 8; ++r) {
                acc[r][0].x = fmaf(ar8[r], w0.x, acc[r][0].x);
                acc[r][0].y = fmaf(ar8[r], w0.y, acc[r][0].y);
                acc[r][0].z = fmaf(ar8[r], w0.z, acc[r][0].z);
                acc[r][0].w = fmaf(ar8[r], w0.w, acc[r][0].w);
                acc[r][1].x = fmaf(ar8[r], w1.x, acc[r][1].x);
                acc[r][1].y = fmaf(ar8[r], w1.y, acc[r][1].y);
                acc[r][1].z = fmaf(ar8[r], w1.z, acc[r][1].z);
                acc[r][1].w = fmaf(ar8[r], w1.w, acc[r][1].w);
            }
        }
    }

    float4 b0 = make_float4(0.f, 0.f, 0.f, 0.f), b1 = b0;
    if (HASBIAS) {
        b0 = *(const float4*)&bias[tc * 4];
        b1 = *(const float4*)&bias[NOUT / 2 + tc * 4];
    }
#pragma unroll
    for (int r = 0; r < 8; ++r) {
        int row = rowbase + tr * 8 + r;
        if (row < M) {
            float4 v0 = acc[r][0], v1 = acc[r][1];
            if (HASBIAS) {
            v0.x += b0.x; v0.y += b0.y; v0.z += b0.z; v0.w += b0.w;
            v1.x += b1.x; v1.y += b1.y; v1.z += b1.z; v1.w += b1.w;
            }
            if (HASADD) {
                float4 a0 = *(const float4*)&add[(size_t)row * NOUT + tc * 4];
                float4 a1 = *(const float4*)&add[(size_t)row * NOUT + NOUT / 2 + tc * 4];
                v0.x += a0.x; v0.y += a0.y; v0.z += a0.z; v0.w += a0.w;
                v1.x += a1.x; v1.y += a1.y; v1.z += a1.z; v1.w += a1.w;
            }
            if (RELU) {
                v0.x = fmaxf(v0.x, 0.f); v0.y = fmaxf(v0.y, 0.f);
                v0.z = fmaxf(v0.z, 0.f); v0.w = fmaxf(v0.w, 0.f);
                v1.x = fmaxf(v1.x, 0.f); v1.y = fmaxf(v1.y, 0.f);
                v1.z = fmaxf(v1.z, 0.f); v1.w = fmaxf(v1.w, 0.f);
            }
            *(float4*)&out[(size_t)row * NOUT + tc * 4] = v0;
            *(float4*)&out[(size_t)row * NOUT + NOUT / 2 + tc * 4] = v1;
        }
    }
}

// ---------------------------------------------------------------------------
// Launch
// ---------------------------------------------------------------------------

extern "C" void kernel_launch(void* const* d_in, const int* in_sizes, int n_in,
                              void* d_out, int out_size, void* d_ws, size_t ws_size,
                              hipStream_t stream) {
    const float* x_c    = (const float*)d_in[0];
    const float* x_m    = (const float*)d_in[1];
    const float* W1cm_l = (const float*)d_in[2];
    const float* W1cm_r = (const float*)d_in[3];
    const float* b1_cm  = (const float*)d_in[4];
    const float* W1mc_l = (const float*)d_in[5];
    const float* W1mc_r = (const float*)d_in[6];
    const float* b1_mc  = (const float*)d_in[7];
    // d_in[8..10] = W2cm_l, W2cm_r, b2_cm : dead inputs (never reach the output)
    const float* W2mc_l = (const float*)d_in[11];
    const float* W2mc_r = (const float*)d_in[12];
    const float* b2_mc  = (const float*)d_in[13];
    const float* Wout   = (const float*)d_in[14];
    const float* bout   = (const float*)d_in[15];
    const int* cm_src   = (const int*)d_in[16];
    const int* cm_dst   = (const int*)d_in[17];
    const int* mc_src   = (const int*)d_in[18];
    const int* mc_dst   = (const int*)d_in[19];
    float* out = (float*)d_out;

    char* ws = (char*)d_ws;
    size_t off = 0;
    auto bump = [&](size_t bytes) -> char* {
        off = (off + 255) & ~(size_t)255;
        char* p = ws + off;
        off += bytes;
        return p;
    };
    int* counts = (int*)bump((size_t)NTOT * 4);
    int* ro     = (int*)bump((size_t)(NTOT + 1) * 4);
    int* cursor = (int*)bump((size_t)NTOT * 4);
    int* bsum   = (int*)bump(256 * 4);
    int* bpre   = (int*)bump(256 * 4);
    int* csr    = (int*)bump((size_t)2 * NEDGE * 4);
    float* bufA  = (float*)bump((size_t)NCUST * HID * 4);  // t_agg_m | h_m ; later h_c2
    float* t2    = (float*)bump((size_t)NMERCH * HID * 4);
    float* agg_c = (float*)bump((size_t)NCUST * INM * 4);
    float* aggT2 = (float*)bump((size_t)NCUST * HID * 4);
    float* h_c   = (float*)bump((size_t)NCUST * HID * 4);

    float* t_agg_m = bufA;                          // [NM,128], dead after gemm #1
    float* h_m     = bufA + (size_t)NMERCH * HID;   // [NM,128], dead after t2 gemm
    float* h_c2    = bufA;                          // [NC,128], overlays both

    const int NBLK = (NTOT + 1023) / 1024;  // 147

    // --- CSR build ---
    hipMemsetAsync(counts, 0, (size_t)NTOT * 4, stream);
    hist_kernel<<<(2 * NEDGE + 255) / 256, 256, 0, stream>>>(cm_dst, mc_dst, counts);
    block_sums_kernel<<<NBLK, 256, 0, stream>>>(counts, bsum);
    scan_partials_kernel<<<1, 256, 0, stream>>>(bsum, bpre, NBLK);
    scan_chunks_kernel<<<NBLK, 256, 0, stream>>>(counts, bpre, ro, cursor);
    fill_kernel<<<(2 * NEDGE + 255) / 256, 256, 0, stream>>>(cm_src, cm_dst, mc_src, mc_dst,
                                                             cursor, csr);

    // --- layer 1, cm: h_m = relu(mean_cm(x_c) @ W1cm_l + b1_cm + x_m @ W1cm_r) ---
    agg_cm_kernel<<<NMERCH / 4, 256, 0, stream>>>(x_c, csr, ro, t_agg_m);
    gemm_kernel<128, 64, 128, true, true, false><<<(NMERCH + 127) / 128, 256, 0, stream>>>(
        t_agg_m, x_m, W1cm_l, W1cm_r, b1_cm, nullptr, h_m, NMERCH);

    // --- layer 2 transform-first: t2 = h_m @ W2mc_l (mean is linear) ---
    gemm_kernel<128, 0, 128, false, false, false><<<(NMERCH + 127) / 128, 256, 0, stream>>>(
        h_m, nullptr, W2mc_l, nullptr, nullptr, nullptr, t2, NMERCH);

    // --- fused mc gathers: agg_c = mean_mc(x_m), aggT2 = mean_mc(t2) ---
    agg_mc_kernel<<<NCUST / 4, 256, 0, stream>>>(x_m, t2, csr, ro, agg_c, aggT2);

    // --- layer 1, mc: h_c = relu(agg_c @ W1mc_l + b1_mc + x_c @ W1mc_r) ---
    gemm_kernel<64, 128, 128, true, true, false><<<(NCUST + 127) / 128, 256, 0, stream>>>(
        agg_c, x_c, W1mc_l, W1mc_r, b1_mc, nullptr, h_c, NCUST);

    // --- layer 2: h_c2 = h_c @ W2mc_r + b2_mc + aggT2 ---
    gemm_kernel<128, 0, 128, false, true, true><<<(NCUST + 127) / 128, 256, 0, stream>>>(
        h_c, nullptr, W2mc_r, nullptr, b2_mc, aggT2, h_c2, NCUST);

    // --- output: out = h_c2 @ Wout + bout ---
    gemm_kernel<128, 0, 64, false, true, false><<<(NCUST + 255) / 256, 256, 0, stream>>>(
        h_c2, nullptr, Wout, nullptr, bout, nullptr, out, NCUST);
}

// Round 4
// 703.465 us; speedup vs baseline: 1.9970x; 1.1816x over previous
//
#include <hip/hip_runtime.h>

// Problem constants (match reference).
#define NCUST 100000
#define NMERCH 50000
#define NEDGE 1000000
#define NTOT (NCUST + NMERCH)   // merchants first, then customers
#define HID 128
#define INC 128
#define INM 64
#define OUTD 64

// CSR binning params
#define SHIFT 9
#define BUCKW 512
#define NBUCKET ((NTOT + BUCKW - 1) / BUCKW)  // 293
#define EPB 4096
#define EPT (EPB / 256)  // 16

// ---------------------------------------------------------------------------
// CSR build: histogram -> scan -> binned two-pass fill.
// ---------------------------------------------------------------------------

__global__ __launch_bounds__(256) void hist_kernel(const int* __restrict__ cm_dst,
                                                   const int* __restrict__ mc_dst,
                                                   int* __restrict__ counts) {
    int idx = blockIdx.x * 256 + threadIdx.x;
    if (idx < NEDGE) {
        atomicAdd(&counts[cm_dst[idx]], 1);
    } else if (idx < 2 * NEDGE) {
        atomicAdd(&counts[NMERCH + mc_dst[idx - NEDGE]], 1);
    }
}

__global__ __launch_bounds__(256) void block_sums_kernel(const int* __restrict__ counts,
                                                         int* __restrict__ bsum) {
    int t = threadIdx.x;
    int idx = blockIdx.x * 1024 + t * 4;
    int4 v = make_int4(0, 0, 0, 0);
    if (idx + 3 < NTOT) {
        v = *(const int4*)(counts + idx);
    } else if (idx < NTOT) {
        v.x = counts[idx];
        if (idx + 1 < NTOT) v.y = counts[idx + 1];
        if (idx + 2 < NTOT) v.z = counts[idx + 2];
    }
    int s = v.x + v.y + v.z + v.w;
    __shared__ int sh[256];
    sh[t] = s;
    __syncthreads();
    for (int off = 128; off > 0; off >>= 1) {
        if (t < off) sh[t] += sh[t + off];
        __syncthreads();
    }
    if (t == 0) bsum[blockIdx.x] = sh[0];
}

__global__ __launch_bounds__(256) void scan_partials_kernel(const int* __restrict__ bsum,
                                                            int* __restrict__ bpre, int n) {
    int t = threadIdx.x;
    __shared__ int sh[256];
    int v = (t < n) ? bsum[t] : 0;
    sh[t] = v;
    __syncthreads();
    for (int off = 1; off < 256; off <<= 1) {
        int val = (t >= off) ? sh[t - off] : 0;
        __syncthreads();
        sh[t] += val;
        __syncthreads();
    }
    if (t < n) bpre[t] = sh[t] - v;  // exclusive prefix
}

__global__ __launch_bounds__(256) void scan_chunks_kernel(const int* __restrict__ counts,
                                                          const int* __restrict__ bpre,
                                                          int* __restrict__ ro) {
    int t = threadIdx.x;
    int idx = blockIdx.x * 1024 + t * 4;
    int4 v = make_int4(0, 0, 0, 0);
    if (idx + 3 < NTOT) {
        v = *(const int4*)(counts + idx);
    } else if (idx < NTOT) {
        v.x = counts[idx];
        if (idx + 1 < NTOT) v.y = counts[idx + 1];
        if (idx + 2 < NTOT) v.z = counts[idx + 2];
    }
    int mysum = v.x + v.y + v.z + v.w;
    __shared__ int sh[256];
    sh[t] = mysum;
    __syncthreads();
    for (int off = 1; off < 256; off <<= 1) {
        int val = (t >= off) ? sh[t - off] : 0;
        __syncthreads();
        sh[t] += val;
        __syncthreads();
    }
    int base = bpre[blockIdx.x] + (sh[t] - mysum);
    int p0 = base;
    int p1 = p0 + v.x;
    int p2 = p1 + v.y;
    int p3 = p2 + v.z;
    if (idx < NTOT)     ro[idx]     = p0;
    if (idx + 1 < NTOT) ro[idx + 1] = p1;
    if (idx + 2 < NTOT) ro[idx + 2] = p2;
    if (idx + 3 < NTOT) ro[idx + 3] = p3;
    if (blockIdx.x == 0 && t == 0) ro[NTOT] = 2 * NEDGE;
}

__global__ __launch_bounds__(256) void init_bcur_kernel(const int* __restrict__ ro,
                                                        int* __restrict__ bucket_cursor) {
    int b = blockIdx.x * 256 + threadIdx.x;
    if (b < NBUCKET) bucket_cursor[b] = ro[b << SHIFT];
}

// Pass A: bin (key,src) records into csr-ordered bucket regions. Per-block LDS
// histogram -> one bump-cursor atomic per (block,bucket) -> runs of ~14
// contiguous 8B records per region: HBM write amplification ~1.3x (vs 17x for
// the old random 4B scatter).
__global__ __launch_bounds__(256) void bin_kernel(const int* __restrict__ cm_src,
                                                  const int* __restrict__ cm_dst,
                                                  const int* __restrict__ mc_src,
                                                  const int* __restrict__ mc_dst,
                                                  int* __restrict__ bucket_cursor,
                                                  int2* __restrict__ pairs) {
    __shared__ int lhist[NBUCKET];
    __shared__ int lbase[NBUCKET];
    __shared__ int loff[NBUCKET];
    const int t = threadIdx.x;
    for (int i = t; i < NBUCKET; i += 256) { lhist[i] = 0; loff[i] = 0; }
    __syncthreads();
    const int base = blockIdx.x * EPB;
    int k_[EPT], s_[EPT];
#pragma unroll
    for (int i = 0; i < EPT; ++i) {
        int idx = base + t + i * 256;
        int key = -1, src = 0;
        if (idx < NEDGE) {
            key = cm_dst[idx];
            src = cm_src[idx];
        } else if (idx < 2 * NEDGE) {
            key = NMERCH + mc_dst[idx - NEDGE];
            src = mc_src[idx - NEDGE];
        }
        k_[i] = key;
        s_[i] = src;
        if (key >= 0) atomicAdd(&lhist[key >> SHIFT], 1);
    }
    __syncthreads();
    for (int b = t; b < NBUCKET; b += 256) {
        int c = lhist[b];
        if (c > 0) lbase[b] = atomicAdd(&bucket_cursor[b], c);
    }
    __syncthreads();
#pragma unroll
    for (int i = 0; i < EPT; ++i) {
        if (k_[i] >= 0) {
            int bk = k_[i] >> SHIFT;
            int p = lbase[bk] + atomicAdd(&loff[bk], 1);
            pairs[p] = make_int2(k_[i], s_[i]);
        }
    }
}

// Pass B: one block per bucket; exact positions via LDS cursors; csr writes
// land inside a ~27KB window (L1/L2-local).
__global__ __launch_bounds__(256) void fillb_kernel(const int2* __restrict__ pairs,
                                                    const int* __restrict__ ro,
                                                    int* __restrict__ csr) {
    __shared__ int cur[BUCKW];
    const int b = blockIdx.x, t = threadIdx.x;
    const int kb = b << SHIFT;
    const int ke = (kb + BUCKW < NTOT) ? kb + BUCKW : NTOT;
    for (int i = t; i < ke - kb; i += 256) cur[i] = ro[kb + i];
    __syncthreads();
    const int start = ro[kb];
    const int end = ro[ke];
    for (int i = start + t; i < end; i += 256) {
        int2 rec = pairs[i];
        int p = atomicAdd(&cur[rec.x - kb], 1);
        csr[p] = rec.y;
    }
}

// ---------------------------------------------------------------------------
// Aggregations: one wave per destination node, register accumulate, unroll 4.
// ---------------------------------------------------------------------------

__global__ __launch_bounds__(256) void agg_cm_kernel(const float* __restrict__ xc,
                                                     const int* __restrict__ csr,
                                                     const int* __restrict__ ro,
                                                     float* __restrict__ aggm) {
    int node = blockIdx.x * 4 + (threadIdx.x >> 6);
    int lane = threadIdx.x & 63;
    if (node >= NMERCH) return;
    int start = ro[node], end = ro[node + 1];
    float2 a0 = {0.f, 0.f}, a1 = {0.f, 0.f}, a2 = {0.f, 0.f}, a3 = {0.f, 0.f};
    int e = start;
    for (; e + 4 <= end; e += 4) {
        int s0 = csr[e], s1 = csr[e + 1], s2 = csr[e + 2], s3 = csr[e + 3];
        float2 v0 = *(const float2*)(xc + (size_t)s0 * INC + lane * 2);
        float2 v1 = *(const float2*)(xc + (size_t)s1 * INC + lane * 2);
        float2 v2 = *(const float2*)(xc + (size_t)s2 * INC + lane * 2);
        float2 v3 = *(const float2*)(xc + (size_t)s3 * INC + lane * 2);
        a0.x += v0.x; a0.y += v0.y;
        a1.x += v1.x; a1.y += v1.y;
        a2.x += v2.x; a2.y += v2.y;
        a3.x += v3.x; a3.y += v3.y;
    }
    for (; e < end; ++e) {
        int s0 = csr[e];
        float2 v0 = *(const float2*)(xc + (size_t)s0 * INC + lane * 2);
        a0.x += v0.x; a0.y += v0.y;
    }
    int deg = end - start;
    float cnt = (float)(deg > 0 ? deg : 1);
    float2 o;
    o.x = (a0.x + a1.x + a2.x + a3.x) / cnt;
    o.y = (a0.y + a1.y + a2.y + a3.y) / cnt;
    *(float2*)(aggm + (size_t)node * HID + lane * 2) = o;
}

__global__ __launch_bounds__(256) void agg_mc_kernel(const float* __restrict__ xm,
                                                     const float* __restrict__ t2,
                                                     const int* __restrict__ csr,
                                                     const int* __restrict__ ro,
                                                     float* __restrict__ agg_c,
                                                     float* __restrict__ aggT2) {
    int node = blockIdx.x * 4 + (threadIdx.x >> 6);
    int lane = threadIdx.x & 63;
    if (node >= NCUST) return;
    int start = ro[NMERCH + node], end = ro[NMERCH + node + 1];
    float a0 = 0.f, a1 = 0.f, a2 = 0.f, a3 = 0.f;
    float2 h0 = {0.f, 0.f}, h1 = {0.f, 0.f}, h2 = {0.f, 0.f}, h3 = {0.f, 0.f};
    int e = start;
    for (; e + 4 <= end; e += 4) {
        int s0 = csr[e], s1 = csr[e + 1], s2 = csr[e + 2], s3 = csr[e + 3];
        a0 += xm[(size_t)s0 * INM + lane];
        a1 += xm[(size_t)s1 * INM + lane];
        a2 += xm[(size_t)s2 * INM + lane];
        a3 += xm[(size_t)s3 * INM + lane];
        float2 v0 = *(const float2*)(t2 + (size_t)s0 * HID + lane * 2);
        float2 v1 = *(const float2*)(t2 + (size_t)s1 * HID + lane * 2);
        float2 v2 = *(const float2*)(t2 + (size_t)s2 * HID + lane * 2);
        float2 v3 = *(const float2*)(t2 + (size_t)s3 * HID + lane * 2);
        h0.x += v0.x; h0.y += v0.y;
        h1.x += v1.x; h1.y += v1.y;
        h2.x += v2.x; h2.y += v2.y;
        h3.x += v3.x; h3.y += v3.y;
    }
    for (; e < end; ++e) {
        int s0 = csr[e];
        a0 += xm[(size_t)s0 * INM + lane];
        float2 v0 = *(const float2*)(t2 + (size_t)s0 * HID + lane * 2);
        h0.x += v0.x; h0.y += v0.y;
    }
    int deg = end - start;
    float cnt = (float)(deg > 0 ? deg : 1);
    agg_c[(size_t)node * INM + lane] = (a0 + a1 + a2 + a3) / cnt;
    float2 o;
    o.x = (h0.x + h1.x + h2.x + h3.x) / cnt;
    o.y = (h0.y + h1.y + h2.y + h3.y) / cnt;
    *(float2*)(aggT2 + (size_t)node * HID + lane * 2) = o;
}

// ---------------------------------------------------------------------------
// Register-tiled fp32 GEMM with fused concat-K (two A operands, two weights):
//   out[M,NOUT] = [relu]( A[M,KA]@WA + B[M,KB]@WB (+bias) )
// ---------------------------------------------------------------------------

template <int KA, int KB, int NOUT, bool RELU, bool HASBIAS>
__global__ __launch_bounds__(256) void gemm_kernel(const float* __restrict__ A,
                                                   const float* __restrict__ B,
                                                   const float* __restrict__ WA,
                                                   const float* __restrict__ WB,
                                                   const float* __restrict__ bias,
                                                   float* __restrict__ out, int M) {
    constexpr int CG = NOUT / 8;    // col-groups
    constexpr int RG = 256 / CG;    // row-groups
    constexpr int TROWS = RG * 8;   // tile rows
    constexpr int NFA = TROWS / 64; // A float4 per thread per k-step
    constexpr int NFW = NOUT / 64;  // W float4 per thread per k-step
    constexpr int AST = TROWS + 4;  // padded LDS stride
    constexpr int NSA = KA / 16, NSB = KB / 16, NS = NSA + NSB;

    __shared__ float At[16 * AST];
    __shared__ float Wt[16 * NOUT];

    const int t = threadIdx.x;
    const int tc = t % CG;
    const int tr = t / CG;
    const int rowbase = blockIdx.x * TROWS;

    float4 pa[NFA];
    float4 pw[NFW];

    auto gload = [&](int s) {
        const float* asrc;
        const float* wsrc;
        int lda, ks;
        if (s < NSA) { asrc = A; wsrc = WA; lda = KA; ks = s * 16; }
        else         { asrc = B; wsrc = WB; lda = KB; ks = (s - NSA) * 16; }
#pragma unroll
        for (int f = 0; f < NFA; ++f) {
            int idx = t + 256 * f;
            int ar = idx >> 2, akq = idx & 3;
            int grow = rowbase + ar;
            if (grow < M) {
                pa[f] = *(const float4*)&asrc[(size_t)grow * lda + ks + akq * 4];
            } else {
                pa[f] = make_float4(0.f, 0.f, 0.f, 0.f);
            }
        }
#pragma unroll
        for (int f = 0; f < NFW; ++f) {
            int idx = t + 256 * f;
            int wk = idx / (NOUT / 4), wcq = idx % (NOUT / 4);
            pw[f] = *(const float4*)&wsrc[(size_t)(ks + wk) * NOUT + wcq * 4];
        }
    };

    float4 acc[8][2];
#pragma unroll
    for (int r = 0; r < 8; ++r) {
        acc[r][0] = make_float4(0.f, 0.f, 0.f, 0.f);
        acc[r][1] = make_float4(0.f, 0.f, 0.f, 0.f);
    }

    gload(0);
    for (int s = 0; s < NS; ++s) {
        __syncthreads();
#pragma unroll
        for (int f = 0; f < NFA; ++f) {
            int idx = t + 256 * f;
            int ar = idx >> 2, akq = idx & 3;
            At[(akq * 4 + 0) * AST + ar] = pa[f].x;
            At[(akq * 4 + 1) * AST + ar] = pa[f].y;
            At[(akq * 4 + 2) * AST + ar] = pa[f].z;
            At[(akq * 4 + 3) * AST + ar] = pa[f].w;
        }
#pragma unroll
        for (int f = 0; f < NFW; ++f) {
            int idx = t + 256 * f;
            int wk = idx / (NOUT / 4), wcq = idx % (NOUT / 4);
            *(float4*)&Wt[wk * NOUT + wcq * 4] = pw[f];
        }
        if (s + 1 < NS) gload(s + 1);
        __syncthreads();
#pragma unroll
        for (int k = 0; k < 16; ++k) {
            float4 av0 = *(const float4*)&At[k * AST + tr * 8];
            float4 av1 = *(const float4*)&At[k * AST + tr * 8 + 4];
            float4 w0 = *(const float4*)&Wt[k * NOUT + tc * 4];
            float4 w1 = *(const float4*)&Wt[k * NOUT + NOUT / 2 + tc * 4];
            const float ar8[8] = {av0.x, av0.y, av0.z, av0.w, av1.x, av1.y, av1.z, av1.w};
#pragma unroll
            for (int r = 0; r < 8; ++r) {
                acc[r][0].x = fmaf(ar8[r], w0.x, acc[r][0].x);
                acc[r][0].y = fmaf(ar8[r], w0.y, acc[r][0].y);
                acc[r][0].z = fmaf(ar8[r], w0.z, acc[r][0].z);
                acc[r][0].w = fmaf(ar8[r], w0.w, acc[r][0].w);
                acc[r][1].x = fmaf(ar8[r], w1.x, acc[r][1].x);
                acc[r][1].y = fmaf(ar8[r], w1.y, acc[r][1].y);
                acc[r][1].z = fmaf(ar8[r], w1.z, acc[r][1].z);
                acc[r][1].w = fmaf(ar8[r], w1.w, acc[r][1].w);
            }
        }
    }

    float4 b0 = make_float4(0.f, 0.f, 0.f, 0.f), b1 = b0;
    if (HASBIAS) {
        b0 = *(const float4*)&bias[tc * 4];
        b1 = *(const float4*)&bias[NOUT / 2 + tc * 4];
    }
#pragma unroll
    for (int r = 0; r < 8; ++r) {
        int row = rowbase + tr * 8 + r;
        if (row < M) {
            float4 v0 = acc[r][0], v1 = acc[r][1];
            if (HASBIAS) {
                v0.x += b0.x; v0.y += b0.y; v0.z += b0.z; v0.w += b0.w;
                v1.x += b1.x; v1.y += b1.y; v1.z += b1.z; v1.w += b1.w;
            }
            if (RELU) {
                v0.x = fmaxf(v0.x, 0.f); v0.y = fmaxf(v0.y, 0.f);
                v0.z = fmaxf(v0.z, 0.f); v0.w = fmaxf(v0.w, 0.f);
                v1.x = fmaxf(v1.x, 0.f); v1.y = fmaxf(v1.y, 0.f);
                v1.z = fmaxf(v1.z, 0.f); v1.w = fmaxf(v1.w, 0.f);
            }
            *(float4*)&out[(size_t)row * NOUT + tc * 4] = v0;
            *(float4*)&out[(size_t)row * NOUT + NOUT / 2 + tc * 4] = v1;
        }
    }
}

// b' = b2_mc @ Wout + bout  (64 threads)
__global__ void bprime_kernel(const float* __restrict__ b2, const float* __restrict__ Wout,
                              const float* __restrict__ bout, float* __restrict__ bprime) {
    int j = threadIdx.x;
    float acc = bout[j];
    for (int k = 0; k < HID; ++k) acc = fmaf(b2[k], Wout[k * OUTD + j], acc);
    bprime[j] = acc;
}

// ---------------------------------------------------------------------------
// Launch
// ---------------------------------------------------------------------------

extern "C" void kernel_launch(void* const* d_in, const int* in_sizes, int n_in,
                              void* d_out, int out_size, void* d_ws, size_t ws_size,
                              hipStream_t stream) {
    const float* x_c    = (const float*)d_in[0];
    const float* x_m    = (const float*)d_in[1];
    const float* W1cm_l = (const float*)d_in[2];
    const float* W1cm_r = (const float*)d_in[3];
    const float* b1_cm  = (const float*)d_in[4];
    const float* W1mc_l = (const float*)d_in[5];
    const float* W1mc_r = (const float*)d_in[6];
    const float* b1_mc  = (const float*)d_in[7];
    // d_in[8..10] = W2cm_l, W2cm_r, b2_cm : dead inputs
    const float* W2mc_l = (const float*)d_in[11];
    const float* W2mc_r = (const float*)d_in[12];
    const float* b2_mc  = (const float*)d_in[13];
    const float* Wout   = (const float*)d_in[14];
    const float* bout   = (const float*)d_in[15];
    const int* cm_src   = (const int*)d_in[16];
    const int* cm_dst   = (const int*)d_in[17];
    const int* mc_src   = (const int*)d_in[18];
    const int* mc_dst   = (const int*)d_in[19];
    float* out = (float*)d_out;

    char* ws = (char*)d_ws;
    size_t off = 0;
    auto bump = [&](size_t bytes) -> char* {
        off = (off + 255) & ~(size_t)255;
        char* p = ws + off;
        off += bytes;
        return p;
    };
    int* counts  = (int*)bump((size_t)NTOT * 4);
    int* ro      = (int*)bump((size_t)(NTOT + 1) * 4);
    int* bcur    = (int*)bump((size_t)NBUCKET * 4);
    int* bsum    = (int*)bump(256 * 4);
    int* bpre    = (int*)bump(256 * 4);
    int* csr     = (int*)bump((size_t)2 * NEDGE * 4);
    float* bufA  = (float*)bump((size_t)NCUST * HID * 4);  // t_agg_m | h_m
    float* t2    = (float*)bump((size_t)NMERCH * HID * 4);
    float* agg_c = (float*)bump((size_t)NCUST * INM * 4);
    float* aggT2 = (float*)bump((size_t)NCUST * HID * 4);
    float* h_c   = (float*)bump((size_t)NCUST * HID * 4);  // also overlays pairs (disjoint lifetime)
    float* w2ro  = (float*)bump((size_t)HID * OUTD * 4);
    float* bpr   = (float*)bump((size_t)OUTD * 4);

    float* t_agg_m = bufA;                          // [NM,128], dead after gemm #1
    float* h_m     = bufA + (size_t)NMERCH * HID;   // [NM,128], dead after t2 gemm
    int2* pairs    = (int2*)h_c;                    // 16MB, dead before h_c is written

    const int NBLK = (NTOT + 1023) / 1024;  // 147

    // --- precompute folded output weights: w2ro = W2mc_r @ Wout, bpr = b2@Wout+bout ---
    gemm_kernel<128, 0, 64, false, false><<<1, 256, 0, stream>>>(
        W2mc_r, nullptr, Wout, nullptr, nullptr, w2ro, HID);
    bprime_kernel<<<1, 64, 0, stream>>>(b2_mc, Wout, bout, bpr);

    // --- CSR build ---
    hipMemsetAsync(counts, 0, (size_t)NTOT * 4, stream);
    hist_kernel<<<(2 * NEDGE + 255) / 256, 256, 0, stream>>>(cm_dst, mc_dst, counts);
    block_sums_kernel<<<NBLK, 256, 0, stream>>>(counts, bsum);
    scan_partials_kernel<<<1, 256, 0, stream>>>(bsum, bpre, NBLK);
    scan_chunks_kernel<<<NBLK, 256, 0, stream>>>(counts, bpre, ro);
    init_bcur_kernel<<<(NBUCKET + 255) / 256, 256, 0, stream>>>(ro, bcur);
    bin_kernel<<<(2 * NEDGE + EPB - 1) / EPB, 256, 0, stream>>>(cm_src, cm_dst, mc_src, mc_dst,
                                                                bcur, pairs);
    fillb_kernel<<<NBUCKET, 256, 0, stream>>>(pairs, ro, csr);

    // --- layer 1, cm: h_m = relu(mean_cm(x_c) @ W1cm_l + b1_cm + x_m @ W1cm_r) ---
    agg_cm_kernel<<<NMERCH / 4, 256, 0, stream>>>(x_c, csr, ro, t_agg_m);
    gemm_kernel<128, 64, 128, true, true><<<(NMERCH + 127) / 128, 256, 0, stream>>>(
        t_agg_m, x_m, W1cm_l, W1cm_r, b1_cm, h_m, NMERCH);

    // --- layer 2 transform-first: t2 = h_m @ W2mc_l (mean is linear) ---
    gemm_kernel<128, 0, 128, false, false><<<(NMERCH + 127) / 128, 256, 0, stream>>>(
        h_m, nullptr, W2mc_l, nullptr, nullptr, t2, NMERCH);

    // --- fused mc gathers: agg_c = mean_mc(x_m), aggT2 = mean_mc(t2) ---
    agg_mc_kernel<<<NCUST / 4, 256, 0, stream>>>(x_m, t2, csr, ro, agg_c, aggT2);

    // --- layer 1, mc: h_c = relu(agg_c @ W1mc_l + b1_mc + x_c @ W1mc_r) ---
    gemm_kernel<64, 128, 128, true, true><<<(NCUST + 127) / 128, 256, 0, stream>>>(
        agg_c, x_c, W1mc_l, W1mc_r, b1_mc, h_c, NCUST);

    // --- folded layer-2 + output: out = aggT2 @ Wout + h_c @ (W2mc_r@Wout) + b' ---
    gemm_kernel<128, 128, 64, false, true><<<(NCUST + 255) / 256, 256, 0, stream>>>(
        aggT2, h_c, Wout, w2ro, bpr, out, NCUST);
}

// Round 5
// 636.186 us; speedup vs baseline: 2.2082x; 1.1058x over previous
//
#include <hip/hip_runtime.h>

// Problem constants (match reference).
#define NCUST 100000
#define NMERCH 50000
#define NEDGE 1000000
#define NTOT (NCUST + NMERCH)   // merchants first, then customers
#define HID 128
#define INC 128
#define INM 64
#define OUTD 64

// CSR binning params
#define SHIFT 9
#define BUCKW 512
#define NBUCKET ((NTOT + BUCKW - 1) / BUCKW)  // 293
#define EPB 4096
#define EPT (EPB / 256)  // 16

// ---------------------------------------------------------------------------
// CSR build: histogram -> scan -> binned two-pass fill.
// ---------------------------------------------------------------------------

__global__ __launch_bounds__(256) void hist_kernel(const int* __restrict__ cm_dst,
                                                   const int* __restrict__ mc_dst,
                                                   int* __restrict__ counts) {
    int idx = blockIdx.x * 256 + threadIdx.x;
    if (idx < NEDGE) {
        atomicAdd(&counts[cm_dst[idx]], 1);
    } else if (idx < 2 * NEDGE) {
        atomicAdd(&counts[NMERCH + mc_dst[idx - NEDGE]], 1);
    }
}

__global__ __launch_bounds__(256) void block_sums_kernel(const int* __restrict__ counts,
                                                         int* __restrict__ bsum) {
    int t = threadIdx.x;
    int idx = blockIdx.x * 1024 + t * 4;
    int4 v = make_int4(0, 0, 0, 0);
    if (idx + 3 < NTOT) {
        v = *(const int4*)(counts + idx);
    } else if (idx < NTOT) {
        v.x = counts[idx];
        if (idx + 1 < NTOT) v.y = counts[idx + 1];
        if (idx + 2 < NTOT) v.z = counts[idx + 2];
    }
    int s = v.x + v.y + v.z + v.w;
    __shared__ int sh[256];
    sh[t] = s;
    __syncthreads();
    for (int off = 128; off > 0; off >>= 1) {
        if (t < off) sh[t] += sh[t + off];
        __syncthreads();
    }
    if (t == 0) bsum[blockIdx.x] = sh[0];
}

__global__ __launch_bounds__(256) void scan_partials_kernel(const int* __restrict__ bsum,
                                                            int* __restrict__ bpre, int n) {
    int t = threadIdx.x;
    __shared__ int sh[256];
    int v = (t < n) ? bsum[t] : 0;
    sh[t] = v;
    __syncthreads();
    for (int off = 1; off < 256; off <<= 1) {
        int val = (t >= off) ? sh[t - off] : 0;
        __syncthreads();
        sh[t] += val;
        __syncthreads();
    }
    if (t < n) bpre[t] = sh[t] - v;  // exclusive prefix
}

__global__ __launch_bounds__(256) void scan_chunks_kernel(const int* __restrict__ counts,
                                                          const int* __restrict__ bpre,
                                                          int* __restrict__ ro) {
    int t = threadIdx.x;
    int idx = blockIdx.x * 1024 + t * 4;
    int4 v = make_int4(0, 0, 0, 0);
    if (idx + 3 < NTOT) {
        v = *(const int4*)(counts + idx);
    } else if (idx < NTOT) {
        v.x = counts[idx];
        if (idx + 1 < NTOT) v.y = counts[idx + 1];
        if (idx + 2 < NTOT) v.z = counts[idx + 2];
    }
    int mysum = v.x + v.y + v.z + v.w;
    __shared__ int sh[256];
    sh[t] = mysum;
    __syncthreads();
    for (int off = 1; off < 256; off <<= 1) {
        int val = (t >= off) ? sh[t - off] : 0;
        __syncthreads();
        sh[t] += val;
        __syncthreads();
    }
    int base = bpre[blockIdx.x] + (sh[t] - mysum);
    int p0 = base;
    int p1 = p0 + v.x;
    int p2 = p1 + v.y;
    int p3 = p2 + v.z;
    if (idx < NTOT)     ro[idx]     = p0;
    if (idx + 1 < NTOT) ro[idx + 1] = p1;
    if (idx + 2 < NTOT) ro[idx + 2] = p2;
    if (idx + 3 < NTOT) ro[idx + 3] = p3;
    if (blockIdx.x == 0 && t == 0) ro[NTOT] = 2 * NEDGE;
}

__global__ __launch_bounds__(256) void init_bcur_kernel(const int* __restrict__ ro,
                                                        int* __restrict__ bucket_cursor) {
    int b = blockIdx.x * 256 + threadIdx.x;
    if (b < NBUCKET) bucket_cursor[b] = ro[b << SHIFT];
}

// Pass A: bin (key,src) records into csr-ordered bucket regions.
__global__ __launch_bounds__(256) void bin_kernel(const int* __restrict__ cm_src,
                                                  const int* __restrict__ cm_dst,
                                                  const int* __restrict__ mc_src,
                                                  const int* __restrict__ mc_dst,
                                                  int* __restrict__ bucket_cursor,
                                                  int2* __restrict__ pairs) {
    __shared__ int lhist[NBUCKET];
    __shared__ int lbase[NBUCKET];
    __shared__ int loff[NBUCKET];
    const int t = threadIdx.x;
    for (int i = t; i < NBUCKET; i += 256) { lhist[i] = 0; loff[i] = 0; }
    __syncthreads();
    const int base = blockIdx.x * EPB;
    int k_[EPT], s_[EPT];
#pragma unroll
    for (int i = 0; i < EPT; ++i) {
        int idx = base + t + i * 256;
        int key = -1, src = 0;
        if (idx < NEDGE) {
            key = cm_dst[idx];
            src = cm_src[idx];
        } else if (idx < 2 * NEDGE) {
            key = NMERCH + mc_dst[idx - NEDGE];
            src = mc_src[idx - NEDGE];
        }
        k_[i] = key;
        s_[i] = src;
        if (key >= 0) atomicAdd(&lhist[key >> SHIFT], 1);
    }
    __syncthreads();
    for (int b = t; b < NBUCKET; b += 256) {
        int c = lhist[b];
        if (c > 0) lbase[b] = atomicAdd(&bucket_cursor[b], c);
    }
    __syncthreads();
#pragma unroll
    for (int i = 0; i < EPT; ++i) {
        if (k_[i] >= 0) {
            int bk = k_[i] >> SHIFT;
            int p = lbase[bk] + atomicAdd(&loff[bk], 1);
            pairs[p] = make_int2(k_[i], s_[i]);
        }
    }
}

// Pass B: one block per bucket; exact positions via LDS cursors.
__global__ __launch_bounds__(256) void fillb_kernel(const int2* __restrict__ pairs,
                                                    const int* __restrict__ ro,
                                                    int* __restrict__ csr) {
    __shared__ int cur[BUCKW];
    const int b = blockIdx.x, t = threadIdx.x;
    const int kb = b << SHIFT;
    const int ke = (kb + BUCKW < NTOT) ? kb + BUCKW : NTOT;
    for (int i = t; i < ke - kb; i += 256) cur[i] = ro[kb + i];
    __syncthreads();
    const int start = ro[kb];
    const int end = ro[ke];
    for (int i = start + t; i < end; i += 256) {
        int2 rec = pairs[i];
        int p = atomicAdd(&cur[rec.x - kb], 1);
        csr[p] = rec.y;
    }
}

// ---------------------------------------------------------------------------
// Aggregations: one wave per destination node, register accumulate, unroll 4.
// ---------------------------------------------------------------------------

// mean over cm edges of x_customer rows (128 f32) -> t_agg_m [NM,128]
__global__ __launch_bounds__(256) void agg_cm_kernel(const float* __restrict__ xc,
                                                     const int* __restrict__ csr,
                                                     const int* __restrict__ ro,
                                                     float* __restrict__ aggm) {
    int node = blockIdx.x * 4 + (threadIdx.x >> 6);
    int lane = threadIdx.x & 63;
    if (node >= NMERCH) return;
    int start = ro[node], end = ro[node + 1];
    float2 a0 = {0.f, 0.f}, a1 = {0.f, 0.f}, a2 = {0.f, 0.f}, a3 = {0.f, 0.f};
    int e = start;
    for (; e + 4 <= end; e += 4) {
        int s0 = csr[e], s1 = csr[e + 1], s2 = csr[e + 2], s3 = csr[e + 3];
        float2 v0 = *(const float2*)(xc + (size_t)s0 * INC + lane * 2);
        float2 v1 = *(const float2*)(xc + (size_t)s1 * INC + lane * 2);
        float2 v2 = *(const float2*)(xc + (size_t)s2 * INC + lane * 2);
        float2 v3 = *(const float2*)(xc + (size_t)s3 * INC + lane * 2);
        a0.x += v0.x; a0.y += v0.y;
        a1.x += v1.x; a1.y += v1.y;
        a2.x += v2.x; a2.y += v2.y;
        a3.x += v3.x; a3.y += v3.y;
    }
    for (; e < end; ++e) {
        int s0 = csr[e];
        float2 v0 = *(const float2*)(xc + (size_t)s0 * INC + lane * 2);
        a0.x += v0.x; a0.y += v0.y;
    }
    int deg = end - start;
    float cnt = (float)(deg > 0 ? deg : 1);
    float2 o;
    o.x = (a0.x + a1.x + a2.x + a3.x) / cnt;
    o.y = (a0.y + a1.y + a2.y + a3.y) / cnt;
    *(float2*)(aggm + (size_t)node * HID + lane * 2) = o;
}

// Fused mc gathers, both streams 64-wide now (t2' folded through Wout):
//   agg_c [NC,64] = mean_mc(x_m), aggT2 [NC,64] = mean_mc(t2')
__global__ __launch_bounds__(256) void agg_mc_kernel(const float* __restrict__ xm,
                                                     const float* __restrict__ t2p,
                                                     const int* __restrict__ csr,
                                                     const int* __restrict__ ro,
                                                     float* __restrict__ agg_c,
                                                     float* __restrict__ aggT2) {
    int node = blockIdx.x * 4 + (threadIdx.x >> 6);
    int lane = threadIdx.x & 63;
    if (node >= NCUST) return;
    int start = ro[NMERCH + node], end = ro[NMERCH + node + 1];
    float a0 = 0.f, a1 = 0.f, a2 = 0.f, a3 = 0.f;
    float h0 = 0.f, h1 = 0.f, h2 = 0.f, h3 = 0.f;
    int e = start;
    for (; e + 4 <= end; e += 4) {
        int s0 = csr[e], s1 = csr[e + 1], s2 = csr[e + 2], s3 = csr[e + 3];
        a0 += xm[(size_t)s0 * INM + lane];
        a1 += xm[(size_t)s1 * INM + lane];
        a2 += xm[(size_t)s2 * INM + lane];
        a3 += xm[(size_t)s3 * INM + lane];
        h0 += t2p[(size_t)s0 * OUTD + lane];
        h1 += t2p[(size_t)s1 * OUTD + lane];
        h2 += t2p[(size_t)s2 * OUTD + lane];
        h3 += t2p[(size_t)s3 * OUTD + lane];
    }
    for (; e < end; ++e) {
        int s0 = csr[e];
        a0 += xm[(size_t)s0 * INM + lane];
        h0 += t2p[(size_t)s0 * OUTD + lane];
    }
    int deg = end - start;
    float cnt = (float)(deg > 0 ? deg : 1);
    agg_c[(size_t)node * INM + lane] = (a0 + a1 + a2 + a3) / cnt;
    aggT2[(size_t)node * OUTD + lane] = (h0 + h1 + h2 + h3) / cnt;
}

// ---------------------------------------------------------------------------
// Register-tiled fp32 GEMM, LDS double-buffered (ONE barrier per k-step),
// fused concat-K:  out = [relu]( A[M,KA]@WA + B[M,KB]@WB (+bias) (+add) )
// Thread: 8 rows x 8 cols (two col-quads NOUT/2 apart). Order per step:
// stage(s+1 from regs) -> gload(s+2 into regs) -> compute(s) -> barrier.
// The vmcnt wait in stage(s+1) is covered by compute(s-1)'s ~2048 cycles.
// ---------------------------------------------------------------------------

template <int KA, int KB, int NOUT, bool RELU, bool HASBIAS, bool HASADD>
__global__ __launch_bounds__(256) void gemm_kernel(const float* __restrict__ A,
                                                   const float* __restrict__ B,
                                                   const float* __restrict__ WA,
                                                   const float* __restrict__ WB,
                                                   const float* __restrict__ bias,
                                                   const float* __restrict__ add,
                                                   float* __restrict__ out, int M) {
    constexpr int CG = NOUT / 8;    // col-groups
    constexpr int RG = 256 / CG;    // row-groups
    constexpr int TROWS = RG * 8;   // tile rows (128 @NOUT=128, 256 @NOUT=64)
    constexpr int NFA = TROWS / 64; // A float4 per thread per k-step
    constexpr int NFW = NOUT / 64;  // W float4 per thread per k-step
    constexpr int AST = TROWS + 4;  // padded LDS stride
    constexpr int NSA = KA / 16, NSB = KB / 16, NS = NSA + NSB;

    __shared__ float At[2][16 * AST];
    __shared__ float Wt[2][16 * NOUT];

    const int t = threadIdx.x;
    const int tc = t % CG;
    const int tr = t / CG;
    const int rowbase = blockIdx.x * TROWS;

    float4 pa[NFA];
    float4 pw[NFW];

    auto gload = [&](int s) {
        const float* asrc;
        const float* wsrc;
        int lda, ks;
        if (s < NSA) { asrc = A; wsrc = WA; lda = KA; ks = s * 16; }
        else         { asrc = B; wsrc = WB; lda = KB; ks = (s - NSA) * 16; }
#pragma unroll
        for (int f = 0; f < NFA; ++f) {
            int idx = t + 256 * f;
            int ar = idx >> 2, akq = idx & 3;
            int grow = rowbase + ar;
            if (grow < M) {
                pa[f] = *(const float4*)&asrc[(size_t)grow * lda + ks + akq * 4];
            } else {
                pa[f] = make_float4(0.f, 0.f, 0.f, 0.f);
            }
        }
#pragma unroll
        for (int f = 0; f < NFW; ++f) {
            int idx = t + 256 * f;
            int wk = idx / (NOUT / 4), wcq = idx % (NOUT / 4);
            pw[f] = *(const float4*)&wsrc[(size_t)(ks + wk) * NOUT + wcq * 4];
        }
    };

    auto stage = [&](int bb) {
        float* at = &At[bb][0];
        float* wt = &Wt[bb][0];
#pragma unroll
        for (int f = 0; f < NFA; ++f) {
            int idx = t + 256 * f;
            int ar = idx >> 2, akq = idx & 3;
            at[(akq * 4 + 0) * AST + ar] = pa[f].x;
            at[(akq * 4 + 1) * AST + ar] = pa[f].y;
            at[(akq * 4 + 2) * AST + ar] = pa[f].z;
            at[(akq * 4 + 3) * AST + ar] = pa[f].w;
        }
#pragma unroll
        for (int f = 0; f < NFW; ++f) {
            int idx = t + 256 * f;
            int wk = idx / (NOUT / 4), wcq = idx % (NOUT / 4);
            *(float4*)&wt[wk * NOUT + wcq * 4] = pw[f];
        }
    };

    float4 acc[8][2];
#pragma unroll
    for (int r = 0; r < 8; ++r) {
        acc[r][0] = make_float4(0.f, 0.f, 0.f, 0.f);
        acc[r][1] = make_float4(0.f, 0.f, 0.f, 0.f);
    }

    auto compute = [&](int bb) {
        const float* at = &At[bb][0];
        const float* wt = &Wt[bb][0];
#pragma unroll
        for (int k = 0; k < 16; ++k) {
            float4 av0 = *(const float4*)&at[k * AST + tr * 8];
            float4 av1 = *(const float4*)&at[k * AST + tr * 8 + 4];
            float4 w0 = *(const float4*)&wt[k * NOUT + tc * 4];
            float4 w1 = *(const float4*)&wt[k * NOUT + NOUT / 2 + tc * 4];
            const float ar8[8] = {av0.x, av0.y, av0.z, av0.w, av1.x, av1.y, av1.z, av1.w};
#pragma unroll
            for (int r = 0; r < 8; ++r) {
                acc[r][0].x = fmaf(ar8[r], w0.x, acc[r][0].x);
                acc[r][0].y = fmaf(ar8[r], w0.y, acc[r][0].y);
                acc[r][0].z = fmaf(ar8[r], w0.z, acc[r][0].z);
                acc[r][0].w = fmaf(ar8[r], w0.w, acc[r][0].w);
                acc[r][1].x = fmaf(ar8[r], w1.x, acc[r][1].x);
                acc[r][1].y = fmaf(ar8[r], w1.y, acc[r][1].y);
                acc[r][1].z = fmaf(ar8[r], w1.z, acc[r][1].z);
                acc[r][1].w = fmaf(ar8[r], w1.w, acc[r][1].w);
            }
        }
    };

    gload(0);
    stage(0);
    if (NS > 1) gload(1);
    __syncthreads();
    for (int s = 0; s < NS; ++s) {
        if (s + 1 < NS) stage((s + 1) & 1);
        if (s + 2 < NS) gload(s + 2);
        compute(s & 1);
        __syncthreads();
    }

    float4 b0 = make_float4(0.f, 0.f, 0.f, 0.f), b1 = b0;
    if (HASBIAS) {
        b0 = *(const float4*)&bias[tc * 4];
        b1 = *(const float4*)&bias[NOUT / 2 + tc * 4];
    }
#pragma unroll
    for (int r = 0; r < 8; ++r) {
        int row = rowbase + tr * 8 + r;
        if (row < M) {
            float4 v0 = acc[r][0], v1 = acc[r][1];
            if (HASBIAS) {
                v0.x += b0.x; v0.y += b0.y; v0.z += b0.z; v0.w += b0.w;
                v1.x += b1.x; v1.y += b1.y; v1.z += b1.z; v1.w += b1.w;
            }
            if (HASADD) {
                float4 a0 = *(const float4*)&add[(size_t)row * NOUT + tc * 4];
                float4 a1 = *(const float4*)&add[(size_t)row * NOUT + NOUT / 2 + tc * 4];
                v0.x += a0.x; v0.y += a0.y; v0.z += a0.z; v0.w += a0.w;
                v1.x += a1.x; v1.y += a1.y; v1.z += a1.z; v1.w += a1.w;
            }
            if (RELU) {
                v0.x = fmaxf(v0.x, 0.f); v0.y = fmaxf(v0.y, 0.f);
                v0.z = fmaxf(v0.z, 0.f); v0.w = fmaxf(v0.w, 0.f);
                v1.x = fmaxf(v1.x, 0.f); v1.y = fmaxf(v1.y, 0.f);
                v1.z = fmaxf(v1.z, 0.f); v1.w = fmaxf(v1.w, 0.f);
            }
            *(float4*)&out[(size_t)row * NOUT + tc * 4] = v0;
            *(float4*)&out[(size_t)row * NOUT + NOUT / 2 + tc * 4] = v1;
        }
    }
}

// b' = b2_mc @ Wout + bout  (64 threads)
__global__ void bprime_kernel(const float* __restrict__ b2, const float* __restrict__ Wout,
                              const float* __restrict__ bout, float* __restrict__ bprime) {
    int j = threadIdx.x;
    float acc = bout[j];
    for (int k = 0; k < HID; ++k) acc = fmaf(b2[k], Wout[k * OUTD + j], acc);
    bprime[j] = acc;
}

// ---------------------------------------------------------------------------
// Launch
// ---------------------------------------------------------------------------

extern "C" void kernel_launch(void* const* d_in, const int* in_sizes, int n_in,
                              void* d_out, int out_size, void* d_ws, size_t ws_size,
                              hipStream_t stream) {
    const float* x_c    = (const float*)d_in[0];
    const float* x_m    = (const float*)d_in[1];
    const float* W1cm_l = (const float*)d_in[2];
    const float* W1cm_r = (const float*)d_in[3];
    const float* b1_cm  = (const float*)d_in[4];
    const float* W1mc_l = (const float*)d_in[5];
    const float* W1mc_r = (const float*)d_in[6];
    const float* b1_mc  = (const float*)d_in[7];
    // d_in[8..10] = W2cm_l, W2cm_r, b2_cm : dead inputs
    const float* W2mc_l = (const float*)d_in[11];
    const float* W2mc_r = (const float*)d_in[12];
    const float* b2_mc  = (const float*)d_in[13];
    const float* Wout   = (const float*)d_in[14];
    const float* bout   = (const float*)d_in[15];
    const int* cm_src   = (const int*)d_in[16];
    const int* cm_dst   = (const int*)d_in[17];
    const int* mc_src   = (const int*)d_in[18];
    const int* mc_dst   = (const int*)d_in[19];
    float* out = (float*)d_out;

    char* ws = (char*)d_ws;
    size_t off = 0;
    auto bump = [&](size_t bytes) -> char* {
        off = (off + 255) & ~(size_t)255;
        char* p = ws + off;
        off += bytes;
        return p;
    };
    int* counts  = (int*)bump((size_t)NTOT * 4);
    int* ro      = (int*)bump((size_t)(NTOT + 1) * 4);
    int* bcur    = (int*)bump((size_t)NBUCKET * 4);
    int* bsum    = (int*)bump(256 * 4);
    int* bpre    = (int*)bump(256 * 4);
    int* csr     = (int*)bump((size_t)2 * NEDGE * 4);
    float* bufA  = (float*)bump((size_t)NCUST * HID * 4);  // t_agg_m | h_m
    float* t2p   = (float*)bump((size_t)NMERCH * OUTD * 4);
    float* agg_c = (float*)bump((size_t)NCUST * INM * 4);
    float* aggT2 = (float*)bump((size_t)NCUST * OUTD * 4);
    float* h_c   = (float*)bump((size_t)NCUST * HID * 4);  // overlays pairs (disjoint lifetime)
    float* w2ro  = (float*)bump((size_t)HID * OUTD * 4);
    float* w2lo  = (float*)bump((size_t)HID * OUTD * 4);
    float* bpr   = (float*)bump((size_t)OUTD * 4);

    float* t_agg_m = bufA;                          // [NM,128], dead after gemm #1
    float* h_m     = bufA + (size_t)NMERCH * HID;   // [NM,128], dead after t2p gemm
    int2* pairs    = (int2*)h_c;                    // 16MB, dead before h_c is written

    const int NBLK = (NTOT + 1023) / 1024;  // 147

    // --- precompute folded weights: w2ro = W2mc_r@Wout, w2lo = W2mc_l@Wout, b' ---
    gemm_kernel<128, 0, 64, false, false, false><<<1, 256, 0, stream>>>(
        W2mc_r, nullptr, Wout, nullptr, nullptr, nullptr, w2ro, HID);
    gemm_kernel<128, 0, 64, false, false, false><<<1, 256, 0, stream>>>(
        W2mc_l, nullptr, Wout, nullptr, nullptr, nullptr, w2lo, HID);
    bprime_kernel<<<1, 64, 0, stream>>>(b2_mc, Wout, bout, bpr);

    // --- CSR build ---
    hipMemsetAsync(counts, 0, (size_t)NTOT * 4, stream);
    hist_kernel<<<(2 * NEDGE + 255) / 256, 256, 0, stream>>>(cm_dst, mc_dst, counts);
    block_sums_kernel<<<NBLK, 256, 0, stream>>>(counts, bsum);
    scan_partials_kernel<<<1, 256, 0, stream>>>(bsum, bpre, NBLK);
    scan_chunks_kernel<<<NBLK, 256, 0, stream>>>(counts, bpre, ro);
    init_bcur_kernel<<<(NBUCKET + 255) / 256, 256, 0, stream>>>(ro, bcur);
    bin_kernel<<<(2 * NEDGE + EPB - 1) / EPB, 256, 0, stream>>>(cm_src, cm_dst, mc_src, mc_dst,
                                                                bcur, pairs);
    fillb_kernel<<<NBUCKET, 256, 0, stream>>>(pairs, ro, csr);

    // --- layer 1, cm: h_m = relu(mean_cm(x_c) @ W1cm_l + b1_cm + x_m @ W1cm_r) ---
    agg_cm_kernel<<<NMERCH / 4, 256, 0, stream>>>(x_c, csr, ro, t_agg_m);
    gemm_kernel<128, 64, 128, true, true, false><<<(NMERCH + 127) / 128, 256, 0, stream>>>(
        t_agg_m, x_m, W1cm_l, W1cm_r, b1_cm, nullptr, h_m, NMERCH);

    // --- layer 2 transform-first + Wout-fold: t2' = h_m @ (W2mc_l@Wout)  [NM,64] ---
    gemm_kernel<128, 0, 64, false, false, false><<<(NMERCH + 255) / 256, 256, 0, stream>>>(
        h_m, nullptr, w2lo, nullptr, nullptr, nullptr, t2p, NMERCH);

    // --- fused mc gathers: agg_c = mean_mc(x_m), aggT2 = mean_mc(t2') ---
    agg_mc_kernel<<<NCUST / 4, 256, 0, stream>>>(x_m, t2p, csr, ro, agg_c, aggT2);

    // --- layer 1, mc: h_c = relu(agg_c @ W1mc_l + b1_mc + x_c @ W1mc_r) ---
    gemm_kernel<64, 128, 128, true, true, false><<<(NCUST + 127) / 128, 256, 0, stream>>>(
        agg_c, x_c, W1mc_l, W1mc_r, b1_mc, nullptr, h_c, NCUST);

    // --- folded layer-2 + output: out = h_c @ (W2mc_r@Wout) + aggT2 + b' ---
    gemm_kernel<128, 0, 64, false, true, true><<<(NCUST + 255) / 256, 256, 0, stream>>>(
        h_c, nullptr, w2ro, nullptr, bpr, aggT2, out, NCUST);
}

// Round 6
// 529.637 us; speedup vs baseline: 2.6524x; 1.2012x over previous
//
#include <hip/hip_runtime.h>

// Problem constants (match reference).
#define NCUST 100000
#define NMERCH 50000
#define NEDGE 1000000
#define NTOT (NCUST + NMERCH)   // merchants first, then customers
#define HID 128
#define INC 128
#define INM 64
#define OUTD 64

// CSR binning params
#define SHIFT 9
#define BUCKW 512
#define NBUCKET ((NTOT + BUCKW - 1) / BUCKW)  // 293
#define EPB 4096
#define EPT (EPB / 256)  // 16

typedef __attribute__((ext_vector_type(8))) short s8v;   // 8 bf16 = 4 VGPR
typedef __attribute__((ext_vector_type(4))) float f32x4; // MFMA accumulator

// Split fp32 pair into packed bf16 hi-words and lo-words (truncation split:
// a = hi + lo exactly to ~2^-16 rel; residual al*bl term dropped in MFMA).
__device__ __forceinline__ void splitpair(float a, float b, uint& hw, uint& lw) {
    uint ua = __float_as_uint(a), ub = __float_as_uint(b);
    uint ha = ua & 0xFFFF0000u, hb = ub & 0xFFFF0000u;
    hw = hb | (ua >> 16);
    float ra = a - __uint_as_float(ha);
    float rb = b - __uint_as_float(hb);
    lw = (__float_as_uint(rb) & 0xFFFF0000u) | (__float_as_uint(ra) >> 16);
}

// ---------------------------------------------------------------------------
// CSR build: histogram -> scan -> binned two-pass fill.
// ---------------------------------------------------------------------------

__global__ __launch_bounds__(256) void hist_kernel(const int* __restrict__ cm_dst,
                                                   const int* __restrict__ mc_dst,
                                                   int* __restrict__ counts) {
    int idx = blockIdx.x * 256 + threadIdx.x;
    if (idx < NEDGE) {
        atomicAdd(&counts[cm_dst[idx]], 1);
    } else if (idx < 2 * NEDGE) {
        atomicAdd(&counts[NMERCH + mc_dst[idx - NEDGE]], 1);
    }
}

__global__ __launch_bounds__(256) void block_sums_kernel(const int* __restrict__ counts,
                                                         int* __restrict__ bsum) {
    int t = threadIdx.x;
    int idx = blockIdx.x * 1024 + t * 4;
    int4 v = make_int4(0, 0, 0, 0);
    if (idx + 3 < NTOT) {
        v = *(const int4*)(counts + idx);
    } else if (idx < NTOT) {
        v.x = counts[idx];
        if (idx + 1 < NTOT) v.y = counts[idx + 1];
        if (idx + 2 < NTOT) v.z = counts[idx + 2];
    }
    int s = v.x + v.y + v.z + v.w;
    __shared__ int sh[256];
    sh[t] = s;
    __syncthreads();
    for (int off = 128; off > 0; off >>= 1) {
        if (t < off) sh[t] += sh[t + off];
        __syncthreads();
    }
    if (t == 0) bsum[blockIdx.x] = sh[0];
}

__global__ __launch_bounds__(256) void scan_partials_kernel(const int* __restrict__ bsum,
                                                            int* __restrict__ bpre, int n) {
    int t = threadIdx.x;
    __shared__ int sh[256];
    int v = (t < n) ? bsum[t] : 0;
    sh[t] = v;
    __syncthreads();
    for (int off = 1; off < 256; off <<= 1) {
        int val = (t >= off) ? sh[t - off] : 0;
        __syncthreads();
        sh[t] += val;
        __syncthreads();
    }
    if (t < n) bpre[t] = sh[t] - v;  // exclusive prefix
}

__global__ __launch_bounds__(256) void scan_chunks_kernel(const int* __restrict__ counts,
                                                          const int* __restrict__ bpre,
                                                          int* __restrict__ ro) {
    int t = threadIdx.x;
    int idx = blockIdx.x * 1024 + t * 4;
    int4 v = make_int4(0, 0, 0, 0);
    if (idx + 3 < NTOT) {
        v = *(const int4*)(counts + idx);
    } else if (idx < NTOT) {
        v.x = counts[idx];
        if (idx + 1 < NTOT) v.y = counts[idx + 1];
        if (idx + 2 < NTOT) v.z = counts[idx + 2];
    }
    int mysum = v.x + v.y + v.z + v.w;
    __shared__ int sh[256];
    sh[t] = mysum;
    __syncthreads();
    for (int off = 1; off < 256; off <<= 1) {
        int val = (t >= off) ? sh[t - off] : 0;
        __syncthreads();
        sh[t] += val;
        __syncthreads();
    }
    int base = bpre[blockIdx.x] + (sh[t] - mysum);
    int p0 = base;
    int p1 = p0 + v.x;
    int p2 = p1 + v.y;
    int p3 = p2 + v.z;
    if (idx < NTOT)     ro[idx]     = p0;
    if (idx + 1 < NTOT) ro[idx + 1] = p1;
    if (idx + 2 < NTOT) ro[idx + 2] = p2;
    if (idx + 3 < NTOT) ro[idx + 3] = p3;
    if (blockIdx.x == 0 && t == 0) ro[NTOT] = 2 * NEDGE;
}

__global__ __launch_bounds__(256) void init_bcur_kernel(const int* __restrict__ ro,
                                                        int* __restrict__ bucket_cursor) {
    int b = blockIdx.x * 256 + threadIdx.x;
    if (b < NBUCKET) bucket_cursor[b] = ro[b << SHIFT];
}

// Pass A: bin (key,src) records into csr-ordered bucket regions.
__global__ __launch_bounds__(256) void bin_kernel(const int* __restrict__ cm_src,
                                                  const int* __restrict__ cm_dst,
                                                  const int* __restrict__ mc_src,
                                                  const int* __restrict__ mc_dst,
                                                  int* __restrict__ bucket_cursor,
                                                  int2* __restrict__ pairs) {
    __shared__ int lhist[NBUCKET];
    __shared__ int lbase[NBUCKET];
    __shared__ int loff[NBUCKET];
    const int t = threadIdx.x;
    for (int i = t; i < NBUCKET; i += 256) { lhist[i] = 0; loff[i] = 0; }
    __syncthreads();
    const int base = blockIdx.x * EPB;
    int k_[EPT], s_[EPT];
#pragma unroll
    for (int i = 0; i < EPT; ++i) {
        int idx = base + t + i * 256;
        int key = -1, src = 0;
        if (idx < NEDGE) {
            key = cm_dst[idx];
            src = cm_src[idx];
        } else if (idx < 2 * NEDGE) {
            key = NMERCH + mc_dst[idx - NEDGE];
            src = mc_src[idx - NEDGE];
        }
        k_[i] = key;
        s_[i] = src;
        if (key >= 0) atomicAdd(&lhist[key >> SHIFT], 1);
    }
    __syncthreads();
    for (int b = t; b < NBUCKET; b += 256) {
        int c = lhist[b];
        if (c > 0) lbase[b] = atomicAdd(&bucket_cursor[b], c);
    }
    __syncthreads();
#pragma unroll
    for (int i = 0; i < EPT; ++i) {
        if (k_[i] >= 0) {
            int bk = k_[i] >> SHIFT;
            int p = lbase[bk] + atomicAdd(&loff[bk], 1);
            pairs[p] = make_int2(k_[i], s_[i]);
        }
    }
}

// Pass B: one block per bucket; exact positions via LDS cursors.
__global__ __launch_bounds__(256) void fillb_kernel(const int2* __restrict__ pairs,
                                                    const int* __restrict__ ro,
                                                    int* __restrict__ csr) {
    __shared__ int cur[BUCKW];
    const int b = blockIdx.x, t = threadIdx.x;
    const int kb = b << SHIFT;
    const int ke = (kb + BUCKW < NTOT) ? kb + BUCKW : NTOT;
    for (int i = t; i < ke - kb; i += 256) cur[i] = ro[kb + i];
    __syncthreads();
    const int start = ro[kb];
    const int end = ro[ke];
    for (int i = start + t; i < end; i += 256) {
        int2 rec = pairs[i];
        int p = atomicAdd(&cur[rec.x - kb], 1);
        csr[p] = rec.y;
    }
}

// ---------------------------------------------------------------------------
// Aggregations: one wave per destination node, register accumulate, unroll 4.
// ---------------------------------------------------------------------------

// mean over cm edges of x_customer rows (128 f32) -> t_agg_m [NM,128]
__global__ __launch_bounds__(256) void agg_cm_kernel(const float* __restrict__ xc,
                                                     const int* __restrict__ csr,
                                                     const int* __restrict__ ro,
                                                     float* __restrict__ aggm) {
    int node = blockIdx.x * 4 + (threadIdx.x >> 6);
    int lane = threadIdx.x & 63;
    if (node >= NMERCH) return;
    int start = ro[node], end = ro[node + 1];
    float2 a0 = {0.f, 0.f}, a1 = {0.f, 0.f}, a2 = {0.f, 0.f}, a3 = {0.f, 0.f};
    int e = start;
    for (; e + 4 <= end; e += 4) {
        int s0 = csr[e], s1 = csr[e + 1], s2 = csr[e + 2], s3 = csr[e + 3];
        float2 v0 = *(const float2*)(xc + (size_t)s0 * INC + lane * 2);
        float2 v1 = *(const float2*)(xc + (size_t)s1 * INC + lane * 2);
        float2 v2 = *(const float2*)(xc + (size_t)s2 * INC + lane * 2);
        float2 v3 = *(const float2*)(xc + (size_t)s3 * INC + lane * 2);
        a0.x += v0.x; a0.y += v0.y;
        a1.x += v1.x; a1.y += v1.y;
        a2.x += v2.x; a2.y += v2.y;
        a3.x += v3.x; a3.y += v3.y;
    }
    for (; e < end; ++e) {
        int s0 = csr[e];
        float2 v0 = *(const float2*)(xc + (size_t)s0 * INC + lane * 2);
        a0.x += v0.x; a0.y += v0.y;
    }
    int deg = end - start;
    float cnt = (float)(deg > 0 ? deg : 1);
    float2 o;
    o.x = (a0.x + a1.x + a2.x + a3.x) / cnt;
    o.y = (a0.y + a1.y + a2.y + a3.y) / cnt;
    *(float2*)(aggm + (size_t)node * HID + lane * 2) = o;
}

// Fused mc gathers, both streams 64-wide (t2' folded through Wout):
//   agg_c [NC,64] = mean_mc(x_m), aggT2 [NC,64] = mean_mc(t2')
__global__ __launch_bounds__(256) void agg_mc_kernel(const float* __restrict__ xm,
                                                     const float* __restrict__ t2p,
                                                     const int* __restrict__ csr,
                                                     const int* __restrict__ ro,
                                                     float* __restrict__ agg_c,
                                                     float* __restrict__ aggT2) {
    int node = blockIdx.x * 4 + (threadIdx.x >> 6);
    int lane = threadIdx.x & 63;
    if (node >= NCUST) return;
    int start = ro[NMERCH + node], end = ro[NMERCH + node + 1];
    float a0 = 0.f, a1 = 0.f, a2 = 0.f, a3 = 0.f;
    float h0 = 0.f, h1 = 0.f, h2 = 0.f, h3 = 0.f;
    int e = start;
    for (; e + 4 <= end; e += 4) {
        int s0 = csr[e], s1 = csr[e + 1], s2 = csr[e + 2], s3 = csr[e + 3];
        a0 += xm[(size_t)s0 * INM + lane];
        a1 += xm[(size_t)s1 * INM + lane];
        a2 += xm[(size_t)s2 * INM + lane];
        a3 += xm[(size_t)s3 * INM + lane];
        h0 += t2p[(size_t)s0 * OUTD + lane];
        h1 += t2p[(size_t)s1 * OUTD + lane];
        h2 += t2p[(size_t)s2 * OUTD + lane];
        h3 += t2p[(size_t)s3 * OUTD + lane];
    }
    for (; e < end; ++e) {
        int s0 = csr[e];
        a0 += xm[(size_t)s0 * INM + lane];
        h0 += t2p[(size_t)s0 * OUTD + lane];
    }
    int deg = end - start;
    float cnt = (float)(deg > 0 ? deg : 1);
    agg_c[(size_t)node * INM + lane] = (a0 + a1 + a2 + a3) / cnt;
    aggT2[(size_t)node * OUTD + lane] = (h0 + h1 + h2 + h3) / cnt;
}

// ---------------------------------------------------------------------------
// Small dense helpers (weight folding, run once per launch).
// ---------------------------------------------------------------------------

// o[128][64] = Wa[128][128] @ Wb[128][64]
__global__ __launch_bounds__(64) void small_mm_kernel(const float* __restrict__ Wa,
                                                      const float* __restrict__ Wb,
                                                      float* __restrict__ o) {
    __shared__ float row[128];
    int r = blockIdx.x, j = threadIdx.x;
    for (int k = j; k < 128; k += 64) row[k] = Wa[r * 128 + k];
    __syncthreads();
    float acc = 0.f;
    for (int k = 0; k < 128; ++k) acc = fmaf(row[k], Wb[k * 64 + j], acc);
    o[r * 64 + j] = acc;
}

// b' = b2_mc @ Wout + bout  (64 threads)
__global__ void bprime_kernel(const float* __restrict__ b2, const float* __restrict__ Wout,
                              const float* __restrict__ bout, float* __restrict__ bprime) {
    int j = threadIdx.x;
    float acc = bout[j];
    for (int k = 0; k < HID; ++k) acc = fmaf(b2[k], Wout[k * OUTD + j], acc);
    bprime[j] = acc;
}

// ---------------------------------------------------------------------------
// Weight-plane prep: split each fp32 weight W[K][N] into bf16 hi/lo planes in
// MFMA B-fragment order: plane[(kt*4+kg)*N + n] = 16B of 8 bf16, k = kt*32+kg*8+i.
// Plane offsets (in shorts) inside the 'planes' buffer:
//   W1cm_l h=0      l=16384 | W1cm_r h=32768 l=40960 | W1mc_l h=49152 l=57344
//   W1mc_r h=65536  l=81920 | w2ro   h=98304 l=106496| w2lo   h=114688 l=122880
// ---------------------------------------------------------------------------

__global__ __launch_bounds__(256) void wprep_kernel(const float* __restrict__ w0,
                                                    const float* __restrict__ w1,
                                                    const float* __restrict__ w2,
                                                    const float* __restrict__ w3,
                                                    const float* __restrict__ w4,
                                                    const float* __restrict__ w5,
                                                    short* __restrict__ planes) {
    int b = blockIdx.x;
    const float* src;
    int N, kt, hoff, loff;
    if (b < 4)       { src = w0; N = 128; kt = b;      hoff = 0;      loff = 16384; }
    else if (b < 6)  { src = w1; N = 128; kt = b - 4;  hoff = 32768;  loff = 40960; }
    else if (b < 8)  { src = w2; N = 128; kt = b - 6;  hoff = 49152;  loff = 57344; }
    else if (b < 12) { src = w3; N = 128; kt = b - 8;  hoff = 65536;  loff = 81920; }
    else if (b < 16) { src = w4; N = 64;  kt = b - 12; hoff = 98304;  loff = 106496; }
    else             { src = w5; N = 64;  kt = b - 16; hoff = 114688; loff = 122880; }

    for (int slot = threadIdx.x; slot < N * 4; slot += 256) {
        int n = slot % N, kg = slot / N;
        uint hw[4], lw[4];
#pragma unroll
        for (int p = 0; p < 4; ++p) {
            float a = src[(kt * 32 + kg * 8 + 2 * p) * N + n];
            float c = src[(kt * 32 + kg * 8 + 2 * p + 1) * N + n];
            splitpair(a, c, hw[p], lw[p]);
        }
        size_t eoff = (size_t)((kt * 4 + kg) * N + n) * 8;
        *(int4*)&planes[hoff + eoff] = make_int4(hw[0], hw[1], hw[2], hw[3]);
        *(int4*)&planes[loff + eoff] = make_int4(lw[0], lw[1], lw[2], lw[3]);
    }
}

// ---------------------------------------------------------------------------
// Split-bf16 MFMA GEMM:  out[M,NOUT] = [relu](A[M,KA]@WA + B[M,KB]@WB (+bias)(+add))
// 256 threads = 4 waves (2x2). Block tile 128 x NOUT; wave 64 x NOUT/2.
// A: fp32 global -> register split -> LDS planes [kg][row] (16B entries,
// consecutive-lane-consecutive-16B reads = conflict-free), double-buffered,
// one barrier/ktile. W: pre-split planes read from global (L1/L2-hot).
// Each fragment product uses 3 MFMAs: ah*bh + ah*bl + al*bh (~fp32 accuracy).
// ---------------------------------------------------------------------------

template <int KA, int KB, int NOUT, bool RELU, bool HASBIAS, bool HASADD>
__global__ __launch_bounds__(256) void mfma_gemm(const float* __restrict__ A,
                                                 const float* __restrict__ B,
                                                 const short* __restrict__ WAh,
                                                 const short* __restrict__ WAl,
                                                 const short* __restrict__ WBh,
                                                 const short* __restrict__ WBl,
                                                 const float* __restrict__ bias,
                                                 const float* __restrict__ add,
                                                 float* __restrict__ out, int M) {
    constexpr int NSA = KA / 32, NSB = KB / 32, NS = NSA + NSB;
    constexpr int CBN = NOUT / 32;  // col fragments per wave

    __shared__ int4 AhL[2][512];  // [buf][kg*128 + row], 16B = 8 bf16 (k = kg*8+i)
    __shared__ int4 AlL[2][512];

    const int t = threadIdx.x;
    const int lane = t & 63;
    const int wv = t >> 6;
    const int wr = wv >> 1;  // wave row (0..1)
    const int wc = wv & 1;   // wave col (0..1)
    const int rowbase = blockIdx.x * 128;
    const int srow = t >> 1, kh = t & 1;  // staging: row 0..127, k-half 0..1

    float4 pa[4];

    auto gload = [&](int s) {
        const float* src;
        int lda, ks;
        if (s < NSA) { src = A; lda = KA; ks = s * 32; }
        else         { src = B; lda = KB; ks = (s - NSA) * 32; }
        const int grow = rowbase + srow;
        if (grow < M) {
            const float* p = src + (size_t)grow * lda + ks + kh * 16;
            pa[0] = *(const float4*)(p);
            pa[1] = *(const float4*)(p + 4);
            pa[2] = *(const float4*)(p + 8);
            pa[3] = *(const float4*)(p + 12);
        } else {
            pa[0] = pa[1] = pa[2] = pa[3] = make_float4(0.f, 0.f, 0.f, 0.f);
        }
    };

    auto stage = [&](int bb) {
        uint h[8], l[8];
        splitpair(pa[0].x, pa[0].y, h[0], l[0]);
        splitpair(pa[0].z, pa[0].w, h[1], l[1]);
        splitpair(pa[1].x, pa[1].y, h[2], l[2]);
        splitpair(pa[1].z, pa[1].w, h[3], l[3]);
        splitpair(pa[2].x, pa[2].y, h[4], l[4]);
        splitpair(pa[2].z, pa[2].w, h[5], l[5]);
        splitpair(pa[3].x, pa[3].y, h[6], l[6]);
        splitpair(pa[3].z, pa[3].w, h[7], l[7]);
        const int base0 = (2 * kh) * 128 + srow;  // kg = 2*kh   (els 0-7)
        const int base1 = base0 + 128;            // kg = 2*kh+1 (els 8-15)
        AhL[bb][base0] = make_int4(h[0], h[1], h[2], h[3]);
        AhL[bb][base1] = make_int4(h[4], h[5], h[6], h[7]);
        AlL[bb][base0] = make_int4(l[0], l[1], l[2], l[3]);
        AlL[bb][base1] = make_int4(l[4], l[5], l[6], l[7]);
    };

    f32x4 acc[4][CBN];
#pragma unroll
    for (int rb = 0; rb < 4; ++rb)
#pragma unroll
        for (int cb = 0; cb < CBN; ++cb) acc[rb][cb] = (f32x4){0.f, 0.f, 0.f, 0.f};

    const int kgl = lane >> 4, ln = lane & 15;

    gload(0);
    stage(0);
    for (int s = 0; s < NS; ++s) {
        if (s + 1 < NS) gload(s + 1);
        __syncthreads();
        const short *wph_, *wpl_;
        int wb;
        if (s < NSA) { wph_ = WAh; wpl_ = WAl; wb = s; }
        else         { wph_ = WBh; wpl_ = WBl; wb = s - NSA; }
        const s8v* wph = (const s8v*)wph_;
        const s8v* wpl = (const s8v*)wpl_;
        s8v bh[CBN], bl[CBN];
#pragma unroll
        for (int cb = 0; cb < CBN; ++cb) {
            int n = wc * (NOUT / 2) + cb * 16 + ln;
            int idx = (wb * 4 + kgl) * NOUT + n;
            bh[cb] = wph[idx];
            bl[cb] = wpl[idx];
        }
        const int bb = s & 1;
#pragma unroll
        for (int rb = 0; rb < 4; ++rb) {
            int row = wr * 64 + rb * 16 + ln;
            s8v ah = *(const s8v*)&AhL[bb][kgl * 128 + row];
            s8v al = *(const s8v*)&AlL[bb][kgl * 128 + row];
#pragma unroll
            for (int cb = 0; cb < CBN; ++cb) {
                acc[rb][cb] = __builtin_amdgcn_mfma_f32_16x16x32_bf16(ah, bh[cb], acc[rb][cb], 0, 0, 0);
                acc[rb][cb] = __builtin_amdgcn_mfma_f32_16x16x32_bf16(ah, bl[cb], acc[rb][cb], 0, 0, 0);
                acc[rb][cb] = __builtin_amdgcn_mfma_f32_16x16x32_bf16(al, bh[cb], acc[rb][cb], 0, 0, 0);
            }
        }
        if (s + 1 < NS) stage((s + 1) & 1);
    }

    // Epilogue: D mapping col=lane&15, row=(lane>>4)*4+i  [m89-verified]
#pragma unroll
    for (int cb = 0; cb < CBN; ++cb) {
        int col = wc * (NOUT / 2) + cb * 16 + ln;
        float bv = HASBIAS ? bias[col] : 0.f;
#pragma unroll
        for (int rb = 0; rb < 4; ++rb) {
#pragma unroll
            for (int i = 0; i < 4; ++i) {
                int grow = rowbase + wr * 64 + rb * 16 + kgl * 4 + i;
                if (grow < M) {
                    float o = acc[rb][cb][i] + bv;
                    if (HASADD) o += add[(size_t)grow * NOUT + col];
                    if (RELU) o = fmaxf(o, 0.f);
                    out[(size_t)grow * NOUT + col] = o;
                }
            }
        }
    }
}

// ---------------------------------------------------------------------------
// Launch
// ---------------------------------------------------------------------------

extern "C" void kernel_launch(void* const* d_in, const int* in_sizes, int n_in,
                              void* d_out, int out_size, void* d_ws, size_t ws_size,
                              hipStream_t stream) {
    const float* x_c    = (const float*)d_in[0];
    const float* x_m    = (const float*)d_in[1];
    const float* W1cm_l = (const float*)d_in[2];
    const float* W1cm_r = (const float*)d_in[3];
    const float* b1_cm  = (const float*)d_in[4];
    const float* W1mc_l = (const float*)d_in[5];
    const float* W1mc_r = (const float*)d_in[6];
    const float* b1_mc  = (const float*)d_in[7];
    // d_in[8..10] = W2cm_l, W2cm_r, b2_cm : dead inputs
    const float* W2mc_l = (const float*)d_in[11];
    const float* W2mc_r = (const float*)d_in[12];
    const float* b2_mc  = (const float*)d_in[13];
    const float* Wout   = (const float*)d_in[14];
    const float* bout   = (const float*)d_in[15];
    const int* cm_src   = (const int*)d_in[16];
    const int* cm_dst   = (const int*)d_in[17];
    const int* mc_src   = (const int*)d_in[18];
    const int* mc_dst   = (const int*)d_in[19];
    float* out = (float*)d_out;

    char* ws = (char*)d_ws;
    size_t off = 0;
    auto bump = [&](size_t bytes) -> char* {
        off = (off + 255) & ~(size_t)255;
        char* p = ws + off;
        off += bytes;
        return p;
    };
    int* counts   = (int*)bump((size_t)NTOT * 4);
    int* ro       = (int*)bump((size_t)(NTOT + 1) * 4);
    int* bcur     = (int*)bump((size_t)NBUCKET * 4);
    int* bsum     = (int*)bump(256 * 4);
    int* bpre     = (int*)bump(256 * 4);
    int* csr      = (int*)bump((size_t)2 * NEDGE * 4);
    float* bufA   = (float*)bump((size_t)NCUST * HID * 4);  // t_agg_m | h_m
    float* t2p    = (float*)bump((size_t)NMERCH * OUTD * 4);
    float* agg_c  = (float*)bump((size_t)NCUST * INM * 4);
    float* aggT2  = (float*)bump((size_t)NCUST * OUTD * 4);
    float* h_c    = (float*)bump((size_t)NCUST * HID * 4);  // overlays pairs
    float* w2ro   = (float*)bump((size_t)HID * OUTD * 4);
    float* w2lo   = (float*)bump((size_t)HID * OUTD * 4);
    float* bpr    = (float*)bump((size_t)OUTD * 4);
    short* planes = (short*)bump((size_t)131072 * 2);

    float* t_agg_m = bufA;                          // [NM,128], dead after sage-cm gemm
    float* h_m     = bufA + (size_t)NMERCH * HID;   // [NM,128], dead after t2p gemm
    int2* pairs    = (int2*)h_c;                    // 16MB, dead before h_c is written

    const int NBLK = (NTOT + 1023) / 1024;  // 147

    // --- weight folding + bf16 plane prep ---
    small_mm_kernel<<<128, 64, 0, stream>>>(W2mc_r, Wout, w2ro);
    small_mm_kernel<<<128, 64, 0, stream>>>(W2mc_l, Wout, w2lo);
    bprime_kernel<<<1, 64, 0, stream>>>(b2_mc, Wout, bout, bpr);
    wprep_kernel<<<20, 256, 0, stream>>>(W1cm_l, W1cm_r, W1mc_l, W1mc_r, w2ro, w2lo, planes);

    // --- CSR build ---
    hipMemsetAsync(counts, 0, (size_t)NTOT * 4, stream);
    hist_kernel<<<(2 * NEDGE + 255) / 256, 256, 0, stream>>>(cm_dst, mc_dst, counts);
    block_sums_kernel<<<NBLK, 256, 0, stream>>>(counts, bsum);
    scan_partials_kernel<<<1, 256, 0, stream>>>(bsum, bpre, NBLK);
    scan_chunks_kernel<<<NBLK, 256, 0, stream>>>(counts, bpre, ro);
    init_bcur_kernel<<<(NBUCKET + 255) / 256, 256, 0, stream>>>(ro, bcur);
    bin_kernel<<<(2 * NEDGE + EPB - 1) / EPB, 256, 0, stream>>>(cm_src, cm_dst, mc_src, mc_dst,
                                                                bcur, pairs);
    fillb_kernel<<<NBUCKET, 256, 0, stream>>>(pairs, ro, csr);

    // plane offsets (shorts)
    short* Pcml_h = planes;           short* Pcml_l = planes + 16384;
    short* Pcmr_h = planes + 32768;   short* Pcmr_l = planes + 40960;
    short* Pmcl_h = planes + 49152;   short* Pmcl_l = planes + 57344;
    short* Pmcr_h = planes + 65536;   short* Pmcr_l = planes + 81920;
    short* Pro_h  = planes + 98304;   short* Pro_l  = planes + 106496;
    short* Plo_h  = planes + 114688;  short* Plo_l  = planes + 122880;

    // --- layer 1, cm: h_m = relu(mean_cm(x_c)@W1cm_l + b1_cm + x_m@W1cm_r) ---
    agg_cm_kernel<<<NMERCH / 4, 256, 0, stream>>>(x_c, csr, ro, t_agg_m);
    mfma_gemm<128, 64, 128, true, true, false><<<(NMERCH + 127) / 128, 256, 0, stream>>>(
        t_agg_m, x_m, Pcml_h, Pcml_l, Pcmr_h, Pcmr_l, b1_cm, nullptr, h_m, NMERCH);

    // --- layer 2 transform-first + Wout-fold: t2' = h_m @ (W2mc_l@Wout)  [NM,64] ---
    mfma_gemm<128, 0, 64, false, false, false><<<(NMERCH + 127) / 128, 256, 0, stream>>>(
        h_m, nullptr, Plo_h, Plo_l, nullptr, nullptr, nullptr, nullptr, t2p, NMERCH);

    // --- fused mc gathers: agg_c = mean_mc(x_m), aggT2 = mean_mc(t2') ---
    agg_mc_kernel<<<NCUST / 4, 256, 0, stream>>>(x_m, t2p, csr, ro, agg_c, aggT2);

    // --- layer 1, mc: h_c = relu(agg_c@W1mc_l + b1_mc + x_c@W1mc_r) ---
    mfma_gemm<64, 128, 128, true, true, false><<<(NCUST + 127) / 128, 256, 0, stream>>>(
        agg_c, x_c, Pmcl_h, Pmcl_l, Pmcr_h, Pmcr_l, b1_mc, nullptr, h_c, NCUST);

    // --- folded layer-2 + output: out = h_c @ (W2mc_r@Wout) + aggT2 + b' ---
    mfma_gemm<128, 0, 64, false, true, true><<<(NCUST + 127) / 128, 256, 0, stream>>>(
        h_c, nullptr, Pro_h, Pro_l, nullptr, nullptr, bpr, aggT2, out, NCUST);
}

// Round 7
// 462.068 us; speedup vs baseline: 3.0403x; 1.1462x over previous
//
#include <hip/hip_runtime.h>

// Problem constants (match reference).
#define NCUST 100000
#define NMERCH 50000
#define NEDGE 1000000
#define NTOT (NCUST + NMERCH)   // merchants first, then customers
#define HID 128
#define INC 128
#define INM 64
#define OUTD 64

// CSR binning params
#define SHIFT 9
#define BUCKW 512
#define NBUCKET ((NTOT + BUCKW - 1) / BUCKW)  // 293
#define EPB 4096
#define EPT (EPB / 256)  // 16

typedef __attribute__((ext_vector_type(8))) short s8v;   // 8 bf16 = 4 VGPR
typedef __attribute__((ext_vector_type(4))) float f32x4; // MFMA accumulator

// Split fp32 pair into packed bf16 hi-words and lo-words (truncation split:
// a = hi + lo exactly to ~2^-16 rel; residual al*bl term dropped in MFMA).
__device__ __forceinline__ void splitpair(float a, float b, uint& hw, uint& lw) {
    uint ua = __float_as_uint(a), ub = __float_as_uint(b);
    uint ha = ua & 0xFFFF0000u, hb = ub & 0xFFFF0000u;
    hw = hb | (ua >> 16);
    float ra = a - __uint_as_float(ha);
    float rb = b - __uint_as_float(hb);
    lw = (__float_as_uint(rb) & 0xFFFF0000u) | (__float_as_uint(ra) >> 16);
}

// ---------------------------------------------------------------------------
// CSR build: bucket-count -> bucket-scan -> bin -> fill(+ro).
// No per-node global histogram: per-node offsets are derived inside fillb
// from the binned pairs (LDS hist + LDS scan), eliminating the 2M random
// global atomics (old hist_kernel: 62MB HBM writes for a 600KB array).
// ---------------------------------------------------------------------------

// Per-block LDS histogram over 293 buckets -> one global atomic per bucket.
__global__ __launch_bounds__(256) void bcount_kernel(const int* __restrict__ cm_dst,
                                                     const int* __restrict__ mc_dst,
                                                     int* __restrict__ bcnt) {
    __shared__ int lh[NBUCKET];
    const int t = threadIdx.x;
    for (int i = t; i < NBUCKET; i += 256) lh[i] = 0;
    __syncthreads();
    const int base = blockIdx.x * EPB;
#pragma unroll
    for (int i = 0; i < EPT; ++i) {
        int idx = base + t + i * 256;
        if (idx < NEDGE) {
            atomicAdd(&lh[cm_dst[idx] >> SHIFT], 1);
        } else if (idx < 2 * NEDGE) {
            atomicAdd(&lh[(NMERCH + mc_dst[idx - NEDGE]) >> SHIFT], 1);
        }
    }
    __syncthreads();
    for (int i = t; i < NBUCKET; i += 256) {
        int c = lh[i];
        if (c > 0) atomicAdd(&bcnt[i], c);
    }
}

// Exclusive scan of the 293 bucket counts (one 512-thread block).
__global__ __launch_bounds__(512) void scan_buckets_kernel(const int* __restrict__ bcnt,
                                                           int* __restrict__ bbase,
                                                           int* __restrict__ bcur,
                                                           int* __restrict__ ro) {
    __shared__ int sh[512];
    const int t = threadIdx.x;
    int v = (t < NBUCKET) ? bcnt[t] : 0;
    sh[t] = v;
    __syncthreads();
    for (int off = 1; off < 512; off <<= 1) {
        int x = (t >= off) ? sh[t - off] : 0;
        __syncthreads();
        sh[t] += x;
        __syncthreads();
    }
    if (t < NBUCKET) {
        int e = sh[t] - v;  // exclusive prefix
        bbase[t] = e;
        bcur[t] = e;
    }
    if (t == 0) {
        bbase[NBUCKET] = 2 * NEDGE;
        ro[NTOT] = 2 * NEDGE;
    }
}

// Pass A: bin (key,src) records into csr-ordered bucket regions. Per-block LDS
// histogram -> one bump-cursor atomic per (block,bucket) -> runs of ~14
// contiguous 8B records per flush: write amplification ~1.3x.
__global__ __launch_bounds__(256) void bin_kernel(const int* __restrict__ cm_src,
                                                  const int* __restrict__ cm_dst,
                                                  const int* __restrict__ mc_src,
                                                  const int* __restrict__ mc_dst,
                                                  int* __restrict__ bcur,
                                                  int2* __restrict__ pairs) {
    __shared__ int lhist[NBUCKET];
    __shared__ int lbase[NBUCKET];
    __shared__ int loff[NBUCKET];
    const int t = threadIdx.x;
    for (int i = t; i < NBUCKET; i += 256) { lhist[i] = 0; loff[i] = 0; }
    __syncthreads();
    const int base = blockIdx.x * EPB;
    int k_[EPT], s_[EPT];
#pragma unroll
    for (int i = 0; i < EPT; ++i) {
        int idx = base + t + i * 256;
        int key = -1, src = 0;
        if (idx < NEDGE) {
            key = cm_dst[idx];
            src = cm_src[idx];
        } else if (idx < 2 * NEDGE) {
            key = NMERCH + mc_dst[idx - NEDGE];
            src = mc_src[idx - NEDGE];
        }
        k_[i] = key;
        s_[i] = src;
        if (key >= 0) atomicAdd(&lhist[key >> SHIFT], 1);
    }
    __syncthreads();
    for (int b = t; b < NBUCKET; b += 256) {
        int c = lhist[b];
        if (c > 0) lbase[b] = atomicAdd(&bcur[b], c);
    }
    __syncthreads();
#pragma unroll
    for (int i = 0; i < EPT; ++i) {
        if (k_[i] >= 0) {
            int bk = k_[i] >> SHIFT;
            int p = lbase[bk] + atomicAdd(&loff[bk], 1);
            pairs[p] = make_int2(k_[i], s_[i]);
        }
    }
}

// Pass B: one block per bucket. LDS histogram of the bucket's 512 keys ->
// LDS scan -> per-node ro (global) -> exact-position csr fill (L1-local).
__global__ __launch_bounds__(512) void fillb_kernel(const int2* __restrict__ pairs,
                                                    const int* __restrict__ bbase,
                                                    int* __restrict__ ro,
                                                    int* __restrict__ csr) {
    __shared__ int hist[BUCKW];
    __shared__ int cur[BUCKW];
    const int b = blockIdx.x, t = threadIdx.x;
    const int kb = b << SHIFT;
    const int nk = (kb + BUCKW < NTOT) ? BUCKW : (NTOT - kb);
    hist[t] = 0;
    __syncthreads();
    const int start = bbase[b], end = bbase[b + 1];
    for (int i = start + t; i < end; i += 512) atomicAdd(&hist[pairs[i].x - kb], 1);
    __syncthreads();
    int v = hist[t];
    cur[t] = v;
    __syncthreads();
    for (int off = 1; off < 512; off <<= 1) {
        int x = (t >= off) ? cur[t - off] : 0;
        __syncthreads();
        cur[t] += x;
        __syncthreads();
    }
    int pos = start + cur[t] - v;  // exclusive prefix
    if (t < nk) ro[kb + t] = pos;
    cur[t] = pos;
    __syncthreads();
    for (int i = start + t; i < end; i += 512) {
        int2 rec = pairs[i];
        int p = atomicAdd(&cur[rec.x - kb], 1);
        csr[p] = rec.y;
    }
}

// ---------------------------------------------------------------------------
// Aggregations: one wave per destination node, register accumulate, unroll 4.
// ---------------------------------------------------------------------------

// mean over cm edges of x_customer rows (128 f32) -> t_agg_m [NM,128]
__global__ __launch_bounds__(256) void agg_cm_kernel(const float* __restrict__ xc,
                                                     const int* __restrict__ csr,
                                                     const int* __restrict__ ro,
                                                     float* __restrict__ aggm) {
    int node = blockIdx.x * 4 + (threadIdx.x >> 6);
    int lane = threadIdx.x & 63;
    if (node >= NMERCH) return;
    int start = ro[node], end = ro[node + 1];
    float2 a0 = {0.f, 0.f}, a1 = {0.f, 0.f}, a2 = {0.f, 0.f}, a3 = {0.f, 0.f};
    int e = start;
    for (; e + 4 <= end; e += 4) {
        int s0 = csr[e], s1 = csr[e + 1], s2 = csr[e + 2], s3 = csr[e + 3];
        float2 v0 = *(const float2*)(xc + (size_t)s0 * INC + lane * 2);
        float2 v1 = *(const float2*)(xc + (size_t)s1 * INC + lane * 2);
        float2 v2 = *(const float2*)(xc + (size_t)s2 * INC + lane * 2);
        float2 v3 = *(const float2*)(xc + (size_t)s3 * INC + lane * 2);
        a0.x += v0.x; a0.y += v0.y;
        a1.x += v1.x; a1.y += v1.y;
        a2.x += v2.x; a2.y += v2.y;
        a3.x += v3.x; a3.y += v3.y;
    }
    for (; e < end; ++e) {
        int s0 = csr[e];
        float2 v0 = *(const float2*)(xc + (size_t)s0 * INC + lane * 2);
        a0.x += v0.x; a0.y += v0.y;
    }
    int deg = end - start;
    float cnt = (float)(deg > 0 ? deg : 1);
    float2 o;
    o.x = (a0.x + a1.x + a2.x + a3.x) / cnt;
    o.y = (a0.y + a1.y + a2.y + a3.y) / cnt;
    *(float2*)(aggm + (size_t)node * HID + lane * 2) = o;
}

// Fused mc gathers, both streams 64-wide (t2' folded through Wout):
//   agg_c [NC,64] = mean_mc(x_m), aggT2 [NC,64] = mean_mc(t2')
__global__ __launch_bounds__(256) void agg_mc_kernel(const float* __restrict__ xm,
                                                     const float* __restrict__ t2p,
                                                     const int* __restrict__ csr,
                                                     const int* __restrict__ ro,
                                                     float* __restrict__ agg_c,
                                                     float* __restrict__ aggT2) {
    int node = blockIdx.x * 4 + (threadIdx.x >> 6);
    int lane = threadIdx.x & 63;
    if (node >= NCUST) return;
    int start = ro[NMERCH + node], end = ro[NMERCH + node + 1];
    float a0 = 0.f, a1 = 0.f, a2 = 0.f, a3 = 0.f;
    float h0 = 0.f, h1 = 0.f, h2 = 0.f, h3 = 0.f;
    int e = start;
    for (; e + 4 <= end; e += 4) {
        int s0 = csr[e], s1 = csr[e + 1], s2 = csr[e + 2], s3 = csr[e + 3];
        a0 += xm[(size_t)s0 * INM + lane];
        a1 += xm[(size_t)s1 * INM + lane];
        a2 += xm[(size_t)s2 * INM + lane];
        a3 += xm[(size_t)s3 * INM + lane];
        h0 += t2p[(size_t)s0 * OUTD + lane];
        h1 += t2p[(size_t)s1 * OUTD + lane];
        h2 += t2p[(size_t)s2 * OUTD + lane];
        h3 += t2p[(size_t)s3 * OUTD + lane];
    }
    for (; e < end; ++e) {
        int s0 = csr[e];
        a0 += xm[(size_t)s0 * INM + lane];
        h0 += t2p[(size_t)s0 * OUTD + lane];
    }
    int deg = end - start;
    float cnt = (float)(deg > 0 ? deg : 1);
    agg_c[(size_t)node * INM + lane] = (a0 + a1 + a2 + a3) / cnt;
    aggT2[(size_t)node * OUTD + lane] = (h0 + h1 + h2 + h3) / cnt;
}

// ---------------------------------------------------------------------------
// Small dense helpers (weight folding, run once per launch).
// ---------------------------------------------------------------------------

// o[128][64] = Wa[128][128] @ Wb[128][64]
__global__ __launch_bounds__(64) void small_mm_kernel(const float* __restrict__ Wa,
                                                      const float* __restrict__ Wb,
                                                      float* __restrict__ o) {
    __shared__ float row[128];
    int r = blockIdx.x, j = threadIdx.x;
    for (int k = j; k < 128; k += 64) row[k] = Wa[r * 128 + k];
    __syncthreads();
    float acc = 0.f;
    for (int k = 0; k < 128; ++k) acc = fmaf(row[k], Wb[k * 64 + j], acc);
    o[r * 64 + j] = acc;
}

// b' = b2_mc @ Wout + bout  (64 threads)
__global__ void bprime_kernel(const float* __restrict__ b2, const float* __restrict__ Wout,
                              const float* __restrict__ bout, float* __restrict__ bprime) {
    int j = threadIdx.x;
    float acc = bout[j];
    for (int k = 0; k < HID; ++k) acc = fmaf(b2[k], Wout[k * OUTD + j], acc);
    bprime[j] = acc;
}

// ---------------------------------------------------------------------------
// Weight-plane prep: split each fp32 weight W[K][N] into bf16 hi/lo planes in
// MFMA B-fragment order: plane[(kt*4+kg)*N + n] = 16B of 8 bf16, k = kt*32+kg*8+i.
// ---------------------------------------------------------------------------

__global__ __launch_bounds__(256) void wprep_kernel(const float* __restrict__ w0,
                                                    const float* __restrict__ w1,
                                                    const float* __restrict__ w2,
                                                    const float* __restrict__ w3,
                                                    const float* __restrict__ w4,
                                                    const float* __restrict__ w5,
                                                    short* __restrict__ planes) {
    int b = blockIdx.x;
    const float* src;
    int N, kt, hoff, loff;
    if (b < 4)       { src = w0; N = 128; kt = b;      hoff = 0;      loff = 16384; }
    else if (b < 6)  { src = w1; N = 128; kt = b - 4;  hoff = 32768;  loff = 40960; }
    else if (b < 8)  { src = w2; N = 128; kt = b - 6;  hoff = 49152;  loff = 57344; }
    else if (b < 12) { src = w3; N = 128; kt = b - 8;  hoff = 65536;  loff = 81920; }
    else if (b < 16) { src = w4; N = 64;  kt = b - 12; hoff = 98304;  loff = 106496; }
    else             { src = w5; N = 64;  kt = b - 16; hoff = 114688; loff = 122880; }

    for (int slot = threadIdx.x; slot < N * 4; slot += 256) {
        int n = slot % N, kg = slot / N;
        uint hw[4], lw[4];
#pragma unroll
        for (int p = 0; p < 4; ++p) {
            float a = src[(kt * 32 + kg * 8 + 2 * p) * N + n];
            float c = src[(kt * 32 + kg * 8 + 2 * p + 1) * N + n];
            splitpair(a, c, hw[p], lw[p]);
        }
        size_t eoff = (size_t)((kt * 4 + kg) * N + n) * 8;
        *(int4*)&planes[hoff + eoff] = make_int4(hw[0], hw[1], hw[2], hw[3]);
        *(int4*)&planes[loff + eoff] = make_int4(lw[0], lw[1], lw[2], lw[3]);
    }
}

// ---------------------------------------------------------------------------
// Split-bf16 MFMA GEMM:  out[M,NOUT] = [relu](A[M,KA]@WA + B[M,KB]@WB (+bias)(+add))
// 256 threads = 4 waves (2x2). Block tile 128 x NOUT; wave 64 x NOUT/2.
// A: fp32 global -> register split -> LDS planes [kg][row] (16B entries,
// consecutive-lane-consecutive-16B reads = conflict-free), double-buffered,
// one barrier/ktile. W: pre-split planes read from global (L1/L2-hot).
// Each fragment product uses 3 MFMAs: ah*bh + ah*bl + al*bh (~fp32 accuracy).
// ---------------------------------------------------------------------------

template <int KA, int KB, int NOUT, bool RELU, bool HASBIAS, bool HASADD>
__global__ __launch_bounds__(256) void mfma_gemm(const float* __restrict__ A,
                                                 const float* __restrict__ B,
                                                 const short* __restrict__ WAh,
                                                 const short* __restrict__ WAl,
                                                 const short* __restrict__ WBh,
                                                 const short* __restrict__ WBl,
                                                 const float* __restrict__ bias,
                                                 const float* __restrict__ add,
                                                 float* __restrict__ out, int M) {
    constexpr int NSA = KA / 32, NSB = KB / 32, NS = NSA + NSB;
    constexpr int CBN = NOUT / 32;  // col fragments per wave

    __shared__ int4 AhL[2][512];  // [buf][kg*128 + row], 16B = 8 bf16 (k = kg*8+i)
    __shared__ int4 AlL[2][512];

    const int t = threadIdx.x;
    const int lane = t & 63;
    const int wv = t >> 6;
    const int wr = wv >> 1;  // wave row (0..1)
    const int wc = wv & 1;   // wave col (0..1)
    const int rowbase = blockIdx.x * 128;
    const int srow = t >> 1, kh = t & 1;  // staging: row 0..127, k-half 0..1

    float4 pa[4];

    auto gload = [&](int s) {
        const float* src;
        int lda, ks;
        if (s < NSA) { src = A; lda = KA; ks = s * 32; }
        else         { src = B; lda = KB; ks = (s - NSA) * 32; }
        const int grow = rowbase + srow;
        if (grow < M) {
            const float* p = src + (size_t)grow * lda + ks + kh * 16;
            pa[0] = *(const float4*)(p);
            pa[1] = *(const float4*)(p + 4);
            pa[2] = *(const float4*)(p + 8);
            pa[3] = *(const float4*)(p + 12);
        } else {
            pa[0] = pa[1] = pa[2] = pa[3] = make_float4(0.f, 0.f, 0.f, 0.f);
        }
    };

    auto stage = [&](int bb) {
        uint h[8], l[8];
        splitpair(pa[0].x, pa[0].y, h[0], l[0]);
        splitpair(pa[0].z, pa[0].w, h[1], l[1]);
        splitpair(pa[1].x, pa[1].y, h[2], l[2]);
        splitpair(pa[1].z, pa[1].w, h[3], l[3]);
        splitpair(pa[2].x, pa[2].y, h[4], l[4]);
        splitpair(pa[2].z, pa[2].w, h[5], l[5]);
        splitpair(pa[3].x, pa[3].y, h[6], l[6]);
        splitpair(pa[3].z, pa[3].w, h[7], l[7]);
        const int base0 = (2 * kh) * 128 + srow;  // kg = 2*kh   (els 0-7)
        const int base1 = base0 + 128;            // kg = 2*kh+1 (els 8-15)
        AhL[bb][base0] = make_int4(h[0], h[1], h[2], h[3]);
        AhL[bb][base1] = make_int4(h[4], h[5], h[6], h[7]);
        AlL[bb][base0] = make_int4(l[0], l[1], l[2], l[3]);
        AlL[bb][base1] = make_int4(l[4], l[5], l[6], l[7]);
    };

    f32x4 acc[4][CBN];
#pragma unroll
    for (int rb = 0; rb < 4; ++rb)
#pragma unroll
        for (int cb = 0; cb < CBN; ++cb) acc[rb][cb] = (f32x4){0.f, 0.f, 0.f, 0.f};

    const int kgl = lane >> 4, ln = lane & 15;

    gload(0);
    stage(0);
    for (int s = 0; s < NS; ++s) {
        if (s + 1 < NS) gload(s + 1);
        __syncthreads();
        const short *wph_, *wpl_;
        int wb;
        if (s < NSA) { wph_ = WAh; wpl_ = WAl; wb = s; }
        else         { wph_ = WBh; wpl_ = WBl; wb = s - NSA; }
        const s8v* wph = (const s8v*)wph_;
        const s8v* wpl = (const s8v*)wpl_;
        s8v bh[CBN], bl[CBN];
#pragma unroll
        for (int cb = 0; cb < CBN; ++cb) {
            int n = wc * (NOUT / 2) + cb * 16 + ln;
            int idx = (wb * 4 + kgl) * NOUT + n;
            bh[cb] = wph[idx];
            bl[cb] = wpl[idx];
        }
        const int bb = s & 1;
#pragma unroll
        for (int rb = 0; rb < 4; ++rb) {
            int row = wr * 64 + rb * 16 + ln;
            s8v ah = *(const s8v*)&AhL[bb][kgl * 128 + row];
            s8v al = *(const s8v*)&AlL[bb][kgl * 128 + row];
#pragma unroll
            for (int cb = 0; cb < CBN; ++cb) {
                acc[rb][cb] = __builtin_amdgcn_mfma_f32_16x16x32_bf16(ah, bh[cb], acc[rb][cb], 0, 0, 0);
                acc[rb][cb] = __builtin_amdgcn_mfma_f32_16x16x32_bf16(ah, bl[cb], acc[rb][cb], 0, 0, 0);
                acc[rb][cb] = __builtin_amdgcn_mfma_f32_16x16x32_bf16(al, bh[cb], acc[rb][cb], 0, 0, 0);
            }
        }
        if (s + 1 < NS) stage((s + 1) & 1);
    }

    // Epilogue: D mapping col=lane&15, row=(lane>>4)*4+i  [m89-verified]
#pragma unroll
    for (int cb = 0; cb < CBN; ++cb) {
        int col = wc * (NOUT / 2) + cb * 16 + ln;
        float bv = HASBIAS ? bias[col] : 0.f;
#pragma unroll
        for (int rb = 0; rb < 4; ++rb) {
#pragma unroll
            for (int i = 0; i < 4; ++i) {
                int grow = rowbase + wr * 64 + rb * 16 + kgl * 4 + i;
                if (grow < M) {
                    float o = acc[rb][cb][i] + bv;
                    if (HASADD) o += add[(size_t)grow * NOUT + col];
                    if (RELU) o = fmaxf(o, 0.f);
                    out[(size_t)grow * NOUT + col] = o;
                }
            }
        }
    }
}

// ---------------------------------------------------------------------------
// Launch
// ---------------------------------------------------------------------------

extern "C" void kernel_launch(void* const* d_in, const int* in_sizes, int n_in,
                              void* d_out, int out_size, void* d_ws, size_t ws_size,
                              hipStream_t stream) {
    const float* x_c    = (const float*)d_in[0];
    const float* x_m    = (const float*)d_in[1];
    const float* W1cm_l = (const float*)d_in[2];
    const float* W1cm_r = (const float*)d_in[3];
    const float* b1_cm  = (const float*)d_in[4];
    const float* W1mc_l = (const float*)d_in[5];
    const float* W1mc_r = (const float*)d_in[6];
    const float* b1_mc  = (const float*)d_in[7];
    // d_in[8..10] = W2cm_l, W2cm_r, b2_cm : dead inputs
    const float* W2mc_l = (const float*)d_in[11];
    const float* W2mc_r = (const float*)d_in[12];
    const float* b2_mc  = (const float*)d_in[13];
    const float* Wout   = (const float*)d_in[14];
    const float* bout   = (const float*)d_in[15];
    const int* cm_src   = (const int*)d_in[16];
    const int* cm_dst   = (const int*)d_in[17];
    const int* mc_src   = (const int*)d_in[18];
    const int* mc_dst   = (const int*)d_in[19];
    float* out = (float*)d_out;

    char* ws = (char*)d_ws;
    size_t off = 0;
    auto bump = [&](size_t bytes) -> char* {
        off = (off + 255) & ~(size_t)255;
        char* p = ws + off;
        off += bytes;
        return p;
    };
    int* ro       = (int*)bump((size_t)(NTOT + 1) * 4);
    int* bcnt     = (int*)bump((size_t)NBUCKET * 4);
    int* bbase    = (int*)bump((size_t)(NBUCKET + 1) * 4);
    int* bcur     = (int*)bump((size_t)NBUCKET * 4);
    int* csr      = (int*)bump((size_t)2 * NEDGE * 4);
    float* bufA   = (float*)bump((size_t)NCUST * HID * 4);  // t_agg_m | h_m
    float* t2p    = (float*)bump((size_t)NMERCH * OUTD * 4);
    float* agg_c  = (float*)bump((size_t)NCUST * INM * 4);
    float* aggT2  = (float*)bump((size_t)NCUST * OUTD * 4);
    float* h_c    = (float*)bump((size_t)NCUST * HID * 4);  // overlays pairs
    float* w2ro   = (float*)bump((size_t)HID * OUTD * 4);
    float* w2lo   = (float*)bump((size_t)HID * OUTD * 4);
    float* bpr    = (float*)bump((size_t)OUTD * 4);
    short* planes = (short*)bump((size_t)131072 * 2);

    float* t_agg_m = bufA;                          // [NM,128], dead after sage-cm gemm
    float* h_m     = bufA + (size_t)NMERCH * HID;   // [NM,128], dead after t2p gemm
    int2* pairs    = (int2*)h_c;                    // 16MB, dead before h_c is written

    // --- weight folding + bf16 plane prep ---
    small_mm_kernel<<<128, 64, 0, stream>>>(W2mc_r, Wout, w2ro);
    small_mm_kernel<<<128, 64, 0, stream>>>(W2mc_l, Wout, w2lo);
    bprime_kernel<<<1, 64, 0, stream>>>(b2_mc, Wout, bout, bpr);
    wprep_kernel<<<20, 256, 0, stream>>>(W1cm_l, W1cm_r, W1mc_l, W1mc_r, w2ro, w2lo, planes);

    // --- CSR build (no per-node global histogram) ---
    hipMemsetAsync(bcnt, 0, (size_t)NBUCKET * 4, stream);
    bcount_kernel<<<(2 * NEDGE + EPB - 1) / EPB, 256, 0, stream>>>(cm_dst, mc_dst, bcnt);
    scan_buckets_kernel<<<1, 512, 0, stream>>>(bcnt, bbase, bcur, ro);
    bin_kernel<<<(2 * NEDGE + EPB - 1) / EPB, 256, 0, stream>>>(cm_src, cm_dst, mc_src, mc_dst,
                                                                bcur, pairs);
    fillb_kernel<<<NBUCKET, 512, 0, stream>>>(pairs, bbase, ro, csr);

    // plane offsets (shorts)
    short* Pcml_h = planes;           short* Pcml_l = planes + 16384;
    short* Pcmr_h = planes + 32768;   short* Pcmr_l = planes + 40960;
    short* Pmcl_h = planes + 49152;   short* Pmcl_l = planes + 57344;
    short* Pmcr_h = planes + 65536;   short* Pmcr_l = planes + 81920;
    short* Pro_h  = planes + 98304;   short* Pro_l  = planes + 106496;
    short* Plo_h  = planes + 114688;  short* Plo_l  = planes + 122880;

    // --- layer 1, cm: h_m = relu(mean_cm(x_c)@W1cm_l + b1_cm + x_m@W1cm_r) ---
    agg_cm_kernel<<<NMERCH / 4, 256, 0, stream>>>(x_c, csr, ro, t_agg_m);
    mfma_gemm<128, 64, 128, true, true, false><<<(NMERCH + 127) / 128, 256, 0, stream>>>(
        t_agg_m, x_m, Pcml_h, Pcml_l, Pcmr_h, Pcmr_l, b1_cm, nullptr, h_m, NMERCH);

    // --- layer 2 transform-first + Wout-fold: t2' = h_m @ (W2mc_l@Wout)  [NM,64] ---
    mfma_gemm<128, 0, 64, false, false, false><<<(NMERCH + 127) / 128, 256, 0, stream>>>(
        h_m, nullptr, Plo_h, Plo_l, nullptr, nullptr, nullptr, nullptr, t2p, NMERCH);

    // --- fused mc gathers: agg_c = mean_mc(x_m), aggT2 = mean_mc(t2') ---
    agg_mc_kernel<<<NCUST / 4, 256, 0, stream>>>(x_m, t2p, csr, ro, agg_c, aggT2);

    // --- layer 1, mc: h_c = relu(agg_c@W1mc_l + b1_mc + x_c@W1mc_r) ---
    mfma_gemm<64, 128, 128, true, true, false><<<(NCUST + 127) / 128, 256, 0, stream>>>(
        agg_c, x_c, Pmcl_h, Pmcl_l, Pmcr_h, Pmcr_l, b1_mc, nullptr, h_c, NCUST);

    // --- folded layer-2 + output: out = h_c @ (W2mc_r@Wout) + aggT2 + b' ---
    mfma_gemm<128, 0, 64, false, true, true><<<(NCUST + 127) / 128, 256, 0, stream>>>(
        h_c, nullptr, Pro_h, Pro_l, nullptr, nullptr, bpr, aggT2, out, NCUST);
}

// Round 8
// 428.846 us; speedup vs baseline: 3.2758x; 1.0775x over previous
//
#include <hip/hip_runtime.h>

// Problem constants (match reference).
#define NCUST 100000
#define NMERCH 50000
#define NEDGE 1000000
#define NTOT (NCUST + NMERCH)   // merchants first, then customers
#define HID 128
#define INC 128
#define INM 64
#define OUTD 64

// CSR binning params
#define SHIFT 9
#define BUCKW 512
#define NBUCKET ((NTOT + BUCKW - 1) / BUCKW)  // 293
#define EPB 4096
#define EPT (EPB / 256)  // 16

typedef __attribute__((ext_vector_type(8))) short s8v;   // 8 bf16 = 4 VGPR
typedef __attribute__((ext_vector_type(4))) float f32x4; // MFMA accumulator

// Split fp32 pair into packed bf16 hi-words and lo-words (truncation split:
// a = hi + lo exactly to ~2^-16 rel; residual al*bl term dropped in MFMA).
__device__ __forceinline__ void splitpair(float a, float b, uint& hw, uint& lw) {
    uint ua = __float_as_uint(a), ub = __float_as_uint(b);
    uint ha = ua & 0xFFFF0000u, hb = ub & 0xFFFF0000u;
    hw = hb | (ua >> 16);
    float ra = a - __uint_as_float(ha);
    float rb = b - __uint_as_float(hb);
    lw = (__float_as_uint(rb) & 0xFFFF0000u) | (__float_as_uint(ra) >> 16);
}

// Round-to-nearest-even fp32 -> bf16 bits (unbiased, rel err <= 2^-9).
__device__ __forceinline__ uint f2bfbits(float x) {
    uint u = __float_as_uint(x);
    return (u + 0x7FFFu + ((u >> 16) & 1u)) >> 16;
}
__device__ __forceinline__ uint packbf(float a, float b) {
    return f2bfbits(a) | (f2bfbits(b) << 16);
}
// bf16-pair unpack (exact)
__device__ __forceinline__ float bflo(uint v) { return __uint_as_float(v << 16); }
__device__ __forceinline__ float bfhi(uint v) { return __uint_as_float(v & 0xFFFF0000u); }

// ---------------------------------------------------------------------------
// bf16 gather-table prep.
// ---------------------------------------------------------------------------

// Generic fp32 -> bf16 (RNE), 8 elems/thread.
__global__ __launch_bounds__(256) void tobf_kernel(const float* __restrict__ in,
                                                   ushort* __restrict__ outp, int n8) {
    int i = blockIdx.x * 256 + threadIdx.x;
    if (i >= n8) return;
    const float4* p = (const float4*)in + (size_t)i * 2;
    float4 u = p[0], v = p[1];
    uint4 w;
    w.x = packbf(u.x, u.y);
    w.y = packbf(u.z, u.w);
    w.z = packbf(v.x, v.y);
    w.w = packbf(v.z, v.w);
    ((uint4*)outp)[i] = w;
}

// x_m bf16 into packed table cols 0..63 (cols 64..127 filled by t2p GEMM).
__global__ __launch_bounds__(256) void xmpack_kernel(const float* __restrict__ xm,
                                                     ushort* __restrict__ mcpk) {
    int tid = blockIdx.x * 256 + threadIdx.x;
    if (tid >= NMERCH * 8) return;
    int n = tid >> 3, c = (tid & 7) * 8;
    const float* p = xm + (size_t)n * INM + c;
    float4 u = *(const float4*)p, v = *(const float4*)(p + 4);
    uint4 w;
    w.x = packbf(u.x, u.y);
    w.y = packbf(u.z, u.w);
    w.z = packbf(v.x, v.y);
    w.w = packbf(v.z, v.w);
    *(uint4*)(mcpk + (size_t)n * 128 + c) = w;
}

// ---------------------------------------------------------------------------
// CSR build: bucket-count -> bucket-scan -> bin -> fill(+ro).
// ---------------------------------------------------------------------------

__global__ __launch_bounds__(256) void bcount_kernel(const int* __restrict__ cm_dst,
                                                     const int* __restrict__ mc_dst,
                                                     int* __restrict__ bcnt) {
    __shared__ int lh[NBUCKET];
    const int t = threadIdx.x;
    for (int i = t; i < NBUCKET; i += 256) lh[i] = 0;
    __syncthreads();
    const int base = blockIdx.x * EPB;
#pragma unroll
    for (int i = 0; i < EPT; ++i) {
        int idx = base + t + i * 256;
        if (idx < NEDGE) {
            atomicAdd(&lh[cm_dst[idx] >> SHIFT], 1);
        } else if (idx < 2 * NEDGE) {
            atomicAdd(&lh[(NMERCH + mc_dst[idx - NEDGE]) >> SHIFT], 1);
        }
    }
    __syncthreads();
    for (int i = t; i < NBUCKET; i += 256) {
        int c = lh[i];
        if (c > 0) atomicAdd(&bcnt[i], c);
    }
}

__global__ __launch_bounds__(512) void scan_buckets_kernel(const int* __restrict__ bcnt,
                                                           int* __restrict__ bbase,
                                                           int* __restrict__ bcur,
                                                           int* __restrict__ ro) {
    __shared__ int sh[512];
    const int t = threadIdx.x;
    int v = (t < NBUCKET) ? bcnt[t] : 0;
    sh[t] = v;
    __syncthreads();
    for (int off = 1; off < 512; off <<= 1) {
        int x = (t >= off) ? sh[t - off] : 0;
        __syncthreads();
        sh[t] += x;
        __syncthreads();
    }
    if (t < NBUCKET) {
        int e = sh[t] - v;  // exclusive prefix
        bbase[t] = e;
        bcur[t] = e;
    }
    if (t == 0) {
        bbase[NBUCKET] = 2 * NEDGE;
        ro[NTOT] = 2 * NEDGE;
    }
}

__global__ __launch_bounds__(256) void bin_kernel(const int* __restrict__ cm_src,
                                                  const int* __restrict__ cm_dst,
                                                  const int* __restrict__ mc_src,
                                                  const int* __restrict__ mc_dst,
                                                  int* __restrict__ bcur,
                                                  int2* __restrict__ pairs) {
    __shared__ int lhist[NBUCKET];
    __shared__ int lbase[NBUCKET];
    __shared__ int loff[NBUCKET];
    const int t = threadIdx.x;
    for (int i = t; i < NBUCKET; i += 256) { lhist[i] = 0; loff[i] = 0; }
    __syncthreads();
    const int base = blockIdx.x * EPB;
    int k_[EPT], s_[EPT];
#pragma unroll
    for (int i = 0; i < EPT; ++i) {
        int idx = base + t + i * 256;
        int key = -1, src = 0;
        if (idx < NEDGE) {
            key = cm_dst[idx];
            src = cm_src[idx];
        } else if (idx < 2 * NEDGE) {
            key = NMERCH + mc_dst[idx - NEDGE];
            src = mc_src[idx - NEDGE];
        }
        k_[i] = key;
        s_[i] = src;
        if (key >= 0) atomicAdd(&lhist[key >> SHIFT], 1);
    }
    __syncthreads();
    for (int b = t; b < NBUCKET; b += 256) {
        int c = lhist[b];
        if (c > 0) lbase[b] = atomicAdd(&bcur[b], c);
    }
    __syncthreads();
#pragma unroll
    for (int i = 0; i < EPT; ++i) {
        if (k_[i] >= 0) {
            int bk = k_[i] >> SHIFT;
            int p = lbase[bk] + atomicAdd(&loff[bk], 1);
            pairs[p] = make_int2(k_[i], s_[i]);
        }
    }
}

__global__ __launch_bounds__(512) void fillb_kernel(const int2* __restrict__ pairs,
                                                    const int* __restrict__ bbase,
                                                    int* __restrict__ ro,
                                                    int* __restrict__ csr) {
    __shared__ int hist[BUCKW];
    __shared__ int cur[BUCKW];
    const int b = blockIdx.x, t = threadIdx.x;
    const int kb = b << SHIFT;
    const int nk = (kb + BUCKW < NTOT) ? BUCKW : (NTOT - kb);
    hist[t] = 0;
    __syncthreads();
    const int start = bbase[b], end = bbase[b + 1];
    for (int i = start + t; i < end; i += 512) atomicAdd(&hist[pairs[i].x - kb], 1);
    __syncthreads();
    int v = hist[t];
    cur[t] = v;
    __syncthreads();
    for (int off = 1; off < 512; off <<= 1) {
        int x = (t >= off) ? cur[t - off] : 0;
        __syncthreads();
        cur[t] += x;
        __syncthreads();
    }
    int pos = start + cur[t] - v;  // exclusive prefix
    if (t < nk) ro[kb + t] = pos;
    cur[t] = pos;
    __syncthreads();
    for (int i = start + t; i < end; i += 512) {
        int2 rec = pairs[i];
        int p = atomicAdd(&cur[rec.x - kb], 1);
        csr[p] = rec.y;
    }
}

// ---------------------------------------------------------------------------
// Aggregations: bf16 gather tables, fp32 accumulate, one wave per node.
// ---------------------------------------------------------------------------

// mean over cm edges of xcb rows (128 bf16, 256B) -> t_agg_m [NM,128] fp32
__global__ __launch_bounds__(256) void agg_cm_kernel(const ushort* __restrict__ xcb,
                                                     const int* __restrict__ csr,
                                                     const int* __restrict__ ro,
                                                     float* __restrict__ aggm) {
    int node = blockIdx.x * 4 + (threadIdx.x >> 6);
    int lane = threadIdx.x & 63;
    if (node >= NMERCH) return;
    int start = ro[node], end = ro[node + 1];
    float a0 = 0.f, b0 = 0.f, a1 = 0.f, b1 = 0.f;
    float a2 = 0.f, b2 = 0.f, a3 = 0.f, b3 = 0.f;
    int e = start;
    for (; e + 4 <= end; e += 4) {
        int s0 = csr[e], s1 = csr[e + 1], s2 = csr[e + 2], s3 = csr[e + 3];
        uint v0 = *(const uint*)(xcb + (size_t)s0 * INC + lane * 2);
        uint v1 = *(const uint*)(xcb + (size_t)s1 * INC + lane * 2);
        uint v2 = *(const uint*)(xcb + (size_t)s2 * INC + lane * 2);
        uint v3 = *(const uint*)(xcb + (size_t)s3 * INC + lane * 2);
        a0 += bflo(v0); b0 += bfhi(v0);
        a1 += bflo(v1); b1 += bfhi(v1);
        a2 += bflo(v2); b2 += bfhi(v2);
        a3 += bflo(v3); b3 += bfhi(v3);
    }
    for (; e < end; ++e) {
        uint v0 = *(const uint*)(xcb + (size_t)csr[e] * INC + lane * 2);
        a0 += bflo(v0); b0 += bfhi(v0);
    }
    int deg = end - start;
    float cnt = (float)(deg > 0 ? deg : 1);
    float2 o;
    o.x = (a0 + a1 + a2 + a3) / cnt;
    o.y = (b0 + b1 + b2 + b3) / cnt;
    *(float2*)(aggm + (size_t)node * HID + lane * 2) = o;
}

// Packed mc gather: one 256B row per edge (cols 0-63 = bf16 x_m, 64-127 = bf16 t2').
// Lanes 0-31 accumulate/write agg_c [NC,64]; lanes 32-63 aggT2 [NC,64].
__global__ __launch_bounds__(256) void agg_mc_kernel(const ushort* __restrict__ mcpk,
                                                     const int* __restrict__ csr,
                                                     const int* __restrict__ ro,
                                                     float* __restrict__ agg_c,
                                                     float* __restrict__ aggT2) {
    int node = blockIdx.x * 4 + (threadIdx.x >> 6);
    int lane = threadIdx.x & 63;
    if (node >= NCUST) return;
    int start = ro[NMERCH + node], end = ro[NMERCH + node + 1];
    float a0 = 0.f, b0 = 0.f, a1 = 0.f, b1 = 0.f;
    float a2 = 0.f, b2 = 0.f, a3 = 0.f, b3 = 0.f;
    int e = start;
    for (; e + 4 <= end; e += 4) {
        int s0 = csr[e], s1 = csr[e + 1], s2 = csr[e + 2], s3 = csr[e + 3];
        uint v0 = *(const uint*)(mcpk + (size_t)s0 * 128 + lane * 2);
        uint v1 = *(const uint*)(mcpk + (size_t)s1 * 128 + lane * 2);
        uint v2 = *(const uint*)(mcpk + (size_t)s2 * 128 + lane * 2);
        uint v3 = *(const uint*)(mcpk + (size_t)s3 * 128 + lane * 2);
        a0 += bflo(v0); b0 += bfhi(v0);
        a1 += bflo(v1); b1 += bfhi(v1);
        a2 += bflo(v2); b2 += bfhi(v2);
        a3 += bflo(v3); b3 += bfhi(v3);
    }
    for (; e < end; ++e) {
        uint v0 = *(const uint*)(mcpk + (size_t)csr[e] * 128 + lane * 2);
        a0 += bflo(v0); b0 += bfhi(v0);
    }
    int deg = end - start;
    float cnt = (float)(deg > 0 ? deg : 1);
    float2 o;
    o.x = (a0 + a1 + a2 + a3) / cnt;
    o.y = (b0 + b1 + b2 + b3) / cnt;
    if (lane < 32) {
        *(float2*)(agg_c + (size_t)node * INM + lane * 2) = o;
    } else {
        *(float2*)(aggT2 + (size_t)node * OUTD + (lane - 32) * 2) = o;
    }
}

// ---------------------------------------------------------------------------
// Small dense helpers (weight folding, run once per launch).
// ---------------------------------------------------------------------------

// o[128][64] = Wa[128][128] @ Wb[128][64]
__global__ __launch_bounds__(64) void small_mm_kernel(const float* __restrict__ Wa,
                                                      const float* __restrict__ Wb,
                                                      float* __restrict__ o) {
    __shared__ float row[128];
    int r = blockIdx.x, j = threadIdx.x;
    for (int k = j; k < 128; k += 64) row[k] = Wa[r * 128 + k];
    __syncthreads();
    float acc = 0.f;
    for (int k = 0; k < 128; ++k) acc = fmaf(row[k], Wb[k * 64 + j], acc);
    o[r * 64 + j] = acc;
}

// b' = b2_mc @ Wout + bout  (64 threads)
__global__ void bprime_kernel(const float* __restrict__ b2, const float* __restrict__ Wout,
                              const float* __restrict__ bout, float* __restrict__ bprime) {
    int j = threadIdx.x;
    float acc = bout[j];
    for (int k = 0; k < HID; ++k) acc = fmaf(b2[k], Wout[k * OUTD + j], acc);
    bprime[j] = acc;
}

// ---------------------------------------------------------------------------
// Weight-plane prep: split each fp32 weight W[K][N] into bf16 hi/lo planes in
// MFMA B-fragment order: plane[(kt*4+kg)*N + n] = 16B of 8 bf16, k = kt*32+kg*8+i.
// ---------------------------------------------------------------------------

__global__ __launch_bounds__(256) void wprep_kernel(const float* __restrict__ w0,
                                                    const float* __restrict__ w1,
                                                    const float* __restrict__ w2,
                                                    const float* __restrict__ w3,
                                                    const float* __restrict__ w4,
                                                    const float* __restrict__ w5,
                                                    short* __restrict__ planes) {
    int b = blockIdx.x;
    const float* src;
    int N, kt, hoff, loff;
    if (b < 4)       { src = w0; N = 128; kt = b;      hoff = 0;      loff = 16384; }
    else if (b < 6)  { src = w1; N = 128; kt = b - 4;  hoff = 32768;  loff = 40960; }
    else if (b < 8)  { src = w2; N = 128; kt = b - 6;  hoff = 49152;  loff = 57344; }
    else if (b < 12) { src = w3; N = 128; kt = b - 8;  hoff = 65536;  loff = 81920; }
    else if (b < 16) { src = w4; N = 64;  kt = b - 12; hoff = 98304;  loff = 106496; }
    else             { src = w5; N = 64;  kt = b - 16; hoff = 114688; loff = 122880; }

    for (int slot = threadIdx.x; slot < N * 4; slot += 256) {
        int n = slot % N, kg = slot / N;
        uint hw[4], lw[4];
#pragma unroll
        for (int p = 0; p < 4; ++p) {
            float a = src[(kt * 32 + kg * 8 + 2 * p) * N + n];
            float c = src[(kt * 32 + kg * 8 + 2 * p + 1) * N + n];
            splitpair(a, c, hw[p], lw[p]);
        }
        size_t eoff = (size_t)((kt * 4 + kg) * N + n) * 8;
        *(int4*)&planes[hoff + eoff] = make_int4(hw[0], hw[1], hw[2], hw[3]);
        *(int4*)&planes[loff + eoff] = make_int4(lw[0], lw[1], lw[2], lw[3]);
    }
}

// ---------------------------------------------------------------------------
// Split-bf16 MFMA GEMM:  out[M,NOUT] = [relu](A[M,KA]@WA + B[M,KB]@WB (+bias)(+add))
// OUTBF16: write bf16 (RNE) into outb with row stride oldd (packed-table fill).
// ---------------------------------------------------------------------------

template <int KA, int KB, int NOUT, bool RELU, bool HASBIAS, bool HASADD, bool OUTBF16>
__global__ __launch_bounds__(256) void mfma_gemm(const float* __restrict__ A,
                                                 const float* __restrict__ B,
                                                 const short* __restrict__ WAh,
                                                 const short* __restrict__ WAl,
                                                 const short* __restrict__ WBh,
                                                 const short* __restrict__ WBl,
                                                 const float* __restrict__ bias,
                                                 const float* __restrict__ add,
                                                 float* __restrict__ out,
                                                 ushort* __restrict__ outb, int oldd,
                                                 int M) {
    constexpr int NSA = KA / 32, NSB = KB / 32, NS = NSA + NSB;
    constexpr int CBN = NOUT / 32;  // col fragments per wave

    __shared__ int4 AhL[2][512];  // [buf][kg*128 + row], 16B = 8 bf16 (k = kg*8+i)
    __shared__ int4 AlL[2][512];

    const int t = threadIdx.x;
    const int lane = t & 63;
    const int wv = t >> 6;
    const int wr = wv >> 1;  // wave row (0..1)
    const int wc = wv & 1;   // wave col (0..1)
    const int rowbase = blockIdx.x * 128;
    const int srow = t >> 1, kh = t & 1;  // staging: row 0..127, k-half 0..1

    float4 pa[4];

    auto gload = [&](int s) {
        const float* src;
        int lda, ks;
        if (s < NSA) { src = A; lda = KA; ks = s * 32; }
        else         { src = B; lda = KB; ks = (s - NSA) * 32; }
        const int grow = rowbase + srow;
        if (grow < M) {
            const float* p = src + (size_t)grow * lda + ks + kh * 16;
            pa[0] = *(const float4*)(p);
            pa[1] = *(const float4*)(p + 4);
            pa[2] = *(const float4*)(p + 8);
            pa[3] = *(const float4*)(p + 12);
        } else {
            pa[0] = pa[1] = pa[2] = pa[3] = make_float4(0.f, 0.f, 0.f, 0.f);
        }
    };

    auto stage = [&](int bb) {
        uint h[8], l[8];
        splitpair(pa[0].x, pa[0].y, h[0], l[0]);
        splitpair(pa[0].z, pa[0].w, h[1], l[1]);
        splitpair(pa[1].x, pa[1].y, h[2], l[2]);
        splitpair(pa[1].z, pa[1].w, h[3], l[3]);
        splitpair(pa[2].x, pa[2].y, h[4], l[4]);
        splitpair(pa[2].z, pa[2].w, h[5], l[5]);
        splitpair(pa[3].x, pa[3].y, h[6], l[6]);
        splitpair(pa[3].z, pa[3].w, h[7], l[7]);
        const int base0 = (2 * kh) * 128 + srow;  // kg = 2*kh   (els 0-7)
        const int base1 = base0 + 128;            // kg = 2*kh+1 (els 8-15)
        AhL[bb][base0] = make_int4(h[0], h[1], h[2], h[3]);
        AhL[bb][base1] = make_int4(h[4], h[5], h[6], h[7]);
        AlL[bb][base0] = make_int4(l[0], l[1], l[2], l[3]);
        AlL[bb][base1] = make_int4(l[4], l[5], l[6], l[7]);
    };

    f32x4 acc[4][CBN];
#pragma unroll
    for (int rb = 0; rb < 4; ++rb)
#pragma unroll
        for (int cb = 0; cb < CBN; ++cb) acc[rb][cb] = (f32x4){0.f, 0.f, 0.f, 0.f};

    const int kgl = lane >> 4, ln = lane & 15;

    gload(0);
    stage(0);
    for (int s = 0; s < NS; ++s) {
        if (s + 1 < NS) gload(s + 1);
        __syncthreads();
        const short *wph_, *wpl_;
        int wb;
        if (s < NSA) { wph_ = WAh; wpl_ = WAl; wb = s; }
        else         { wph_ = WBh; wpl_ = WBl; wb = s - NSA; }
        const s8v* wph = (const s8v*)wph_;
        const s8v* wpl = (const s8v*)wpl_;
        s8v bh[CBN], bl[CBN];
#pragma unroll
        for (int cb = 0; cb < CBN; ++cb) {
            int n = wc * (NOUT / 2) + cb * 16 + ln;
            int idx = (wb * 4 + kgl) * NOUT + n;
            bh[cb] = wph[idx];
            bl[cb] = wpl[idx];
        }
        const int bb = s & 1;
#pragma unroll
        for (int rb = 0; rb < 4; ++rb) {
            int row = wr * 64 + rb * 16 + ln;
            s8v ah = *(const s8v*)&AhL[bb][kgl * 128 + row];
            s8v al = *(const s8v*)&AlL[bb][kgl * 128 + row];
#pragma unroll
            for (int cb = 0; cb < CBN; ++cb) {
                acc[rb][cb] = __builtin_amdgcn_mfma_f32_16x16x32_bf16(ah, bh[cb], acc[rb][cb], 0, 0, 0);
                acc[rb][cb] = __builtin_amdgcn_mfma_f32_16x16x32_bf16(ah, bl[cb], acc[rb][cb], 0, 0, 0);
                acc[rb][cb] = __builtin_amdgcn_mfma_f32_16x16x32_bf16(al, bh[cb], acc[rb][cb], 0, 0, 0);
            }
        }
        if (s + 1 < NS) stage((s + 1) & 1);
    }

    // Epilogue: D mapping col=lane&15, row=(lane>>4)*4+i  [m89-verified]
#pragma unroll
    for (int cb = 0; cb < CBN; ++cb) {
        int col = wc * (NOUT / 2) + cb * 16 + ln;
        float bv = HASBIAS ? bias[col] : 0.f;
#pragma unroll
        for (int rb = 0; rb < 4; ++rb) {
#pragma unroll
            for (int i = 0; i < 4; ++i) {
                int grow = rowbase + wr * 64 + rb * 16 + kgl * 4 + i;
                if (grow < M) {
                    float o = acc[rb][cb][i] + bv;
                    if (HASADD) o += add[(size_t)grow * NOUT + col];
                    if (RELU) o = fmaxf(o, 0.f);
                    if (OUTBF16) {
                        outb[(size_t)grow * oldd + col] = (ushort)f2bfbits(o);
                    } else {
                        out[(size_t)grow * NOUT + col] = o;
                    }
                }
            }
        }
    }
}

// ---------------------------------------------------------------------------
// Launch
// ---------------------------------------------------------------------------

extern "C" void kernel_launch(void* const* d_in, const int* in_sizes, int n_in,
                              void* d_out, int out_size, void* d_ws, size_t ws_size,
                              hipStream_t stream) {
    const float* x_c    = (const float*)d_in[0];
    const float* x_m    = (const float*)d_in[1];
    const float* W1cm_l = (const float*)d_in[2];
    const float* W1cm_r = (const float*)d_in[3];
    const float* b1_cm  = (const float*)d_in[4];
    const float* W1mc_l = (const float*)d_in[5];
    const float* W1mc_r = (const float*)d_in[6];
    const float* b1_mc  = (const float*)d_in[7];
    // d_in[8..10] = W2cm_l, W2cm_r, b2_cm : dead inputs
    const float* W2mc_l = (const float*)d_in[11];
    const float* W2mc_r = (const float*)d_in[12];
    const float* b2_mc  = (const float*)d_in[13];
    const float* Wout   = (const float*)d_in[14];
    const float* bout   = (const float*)d_in[15];
    const int* cm_src   = (const int*)d_in[16];
    const int* cm_dst   = (const int*)d_in[17];
    const int* mc_src   = (const int*)d_in[18];
    const int* mc_dst   = (const int*)d_in[19];
    float* out = (float*)d_out;

    char* ws = (char*)d_ws;
    size_t off = 0;
    auto bump = [&](size_t bytes) -> char* {
        off = (off + 255) & ~(size_t)255;
        char* p = ws + off;
        off += bytes;
        return p;
    };
    int* ro       = (int*)bump((size_t)(NTOT + 1) * 4);
    int* bcnt     = (int*)bump((size_t)NBUCKET * 4);
    int* bbase    = (int*)bump((size_t)(NBUCKET + 1) * 4);
    int* bcur     = (int*)bump((size_t)NBUCKET * 4);
    int* csr      = (int*)bump((size_t)2 * NEDGE * 4);
    float* bufA   = (float*)bump((size_t)NCUST * HID * 4);  // t_agg_m | h_m
    float* agg_c  = (float*)bump((size_t)NCUST * INM * 4);
    float* aggT2  = (float*)bump((size_t)NCUST * OUTD * 4);
    float* h_c    = (float*)bump((size_t)NCUST * HID * 4);  // overlays pairs
    float* w2ro   = (float*)bump((size_t)HID * OUTD * 4);
    float* w2lo   = (float*)bump((size_t)HID * OUTD * 4);
    float* bpr    = (float*)bump((size_t)OUTD * 4);
    short* planes = (short*)bump((size_t)131072 * 2);
    ushort* xcb   = (ushort*)bump((size_t)NCUST * INC * 2);  // bf16 x_c (gather table)
    ushort* mcpk  = (ushort*)bump((size_t)NMERCH * 128 * 2); // packed [x_m bf16 | t2' bf16]

    float* t_agg_m = bufA;                          // [NM,128], dead after sage-cm gemm
    float* h_m     = bufA + (size_t)NMERCH * HID;   // [NM,128], dead after t2p gemm
    int2* pairs    = (int2*)h_c;                    // 16MB, dead before h_c is written

    // --- weight folding + bf16 plane/table prep ---
    small_mm_kernel<<<128, 64, 0, stream>>>(W2mc_r, Wout, w2ro);
    small_mm_kernel<<<128, 64, 0, stream>>>(W2mc_l, Wout, w2lo);
    bprime_kernel<<<1, 64, 0, stream>>>(b2_mc, Wout, bout, bpr);
    wprep_kernel<<<20, 256, 0, stream>>>(W1cm_l, W1cm_r, W1mc_l, W1mc_r, w2ro, w2lo, planes);
    tobf_kernel<<<(NCUST * INC / 8 + 255) / 256, 256, 0, stream>>>(x_c, xcb, NCUST * INC / 8);
    xmpack_kernel<<<(NMERCH * 8 + 255) / 256, 256, 0, stream>>>(x_m, mcpk);

    // --- CSR build ---
    hipMemsetAsync(bcnt, 0, (size_t)NBUCKET * 4, stream);
    bcount_kernel<<<(2 * NEDGE + EPB - 1) / EPB, 256, 0, stream>>>(cm_dst, mc_dst, bcnt);
    scan_buckets_kernel<<<1, 512, 0, stream>>>(bcnt, bbase, bcur, ro);
    bin_kernel<<<(2 * NEDGE + EPB - 1) / EPB, 256, 0, stream>>>(cm_src, cm_dst, mc_src, mc_dst,
                                                                bcur, pairs);
    fillb_kernel<<<NBUCKET, 512, 0, stream>>>(pairs, bbase, ro, csr);

    // plane offsets (shorts)
    short* Pcml_h = planes;           short* Pcml_l = planes + 16384;
    short* Pcmr_h = planes + 32768;   short* Pcmr_l = planes + 40960;
    short* Pmcl_h = planes + 49152;   short* Pmcl_l = planes + 57344;
    short* Pmcr_h = planes + 65536;   short* Pmcr_l = planes + 81920;
    short* Pro_h  = planes + 98304;   short* Pro_l  = planes + 106496;
    short* Plo_h  = planes + 114688;  short* Plo_l  = planes + 122880;

    // --- layer 1, cm: h_m = relu(mean_cm(x_c)@W1cm_l + b1_cm + x_m@W1cm_r) ---
    agg_cm_kernel<<<NMERCH / 4, 256, 0, stream>>>(xcb, csr, ro, t_agg_m);
    mfma_gemm<128, 64, 128, true, true, false, false><<<(NMERCH + 127) / 128, 256, 0, stream>>>(
        t_agg_m, x_m, Pcml_h, Pcml_l, Pcmr_h, Pcmr_l, b1_cm, nullptr, h_m, nullptr, 0, NMERCH);

    // --- layer 2 transform-first + Wout-fold: t2' = h_m @ (W2mc_l@Wout), bf16 into mcpk ---
    mfma_gemm<128, 0, 64, false, false, false, true><<<(NMERCH + 127) / 128, 256, 0, stream>>>(
        h_m, nullptr, Plo_h, Plo_l, nullptr, nullptr, nullptr, nullptr, nullptr,
        mcpk + 64, 128, NMERCH);

    // --- fused packed mc gather: agg_c = mean_mc(x_m), aggT2 = mean_mc(t2') ---
    agg_mc_kernel<<<NCUST / 4, 256, 0, stream>>>(mcpk, csr, ro, agg_c, aggT2);

    // --- layer 1, mc: h_c = relu(agg_c@W1mc_l + b1_mc + x_c@W1mc_r) ---
    mfma_gemm<64, 128, 128, true, true, false, false><<<(NCUST + 127) / 128, 256, 0, stream>>>(
        agg_c, x_c, Pmcl_h, Pmcl_l, Pmcr_h, Pmcr_l, b1_mc, nullptr, h_c, nullptr, 0, NCUST);

    // --- folded layer-2 + output: out = h_c @ (W2mc_r@Wout) + aggT2 + b' ---
    mfma_gemm<128, 0, 64, false, true, true, false><<<(NCUST + 127) / 128, 256, 0, stream>>>(
        h_c, nullptr, Pro_h, Pro_l, nullptr, nullptr, bpr, aggT2, out, nullptr, 0, NCUST);
}